// Round 1
// baseline (696.727 us; speedup 1.0000x reference)
//
#include <hip/hip_runtime.h>
#include <hip/hip_bf16.h>

constexpr int HEADS  = 4;
constexpr int HID    = 64;
constexpr int IN_F   = 128;
constexpr int GROUPS = 64;
constexpr float NEG_SLOPE = 0.2f;
constexpr float EPS_SM    = 1e-16f;

static __device__ __forceinline__ float lrelu(float x) { return x >= 0.f ? x : NEG_SLOPE * x; }
static __device__ __forceinline__ float elu1(float x)  { return x > 0.f ? x : expm1f(x); }

// ---------------- GEMM1: h1[N,256] = x[N,128] @ W1[128,256] ----------------
__global__ __launch_bounds__(256) void gemm1_kernel(
    const float* __restrict__ x, const float* __restrict__ W1,
    float* __restrict__ h1, int N) {
  __shared__ float xs[32][IN_F];
  const int t = threadIdx.x;
  const int row0 = blockIdx.x * 32;
  const int rows = min(32, N - row0);
  {
    const float4* xg = reinterpret_cast<const float4*>(x + (size_t)row0 * IN_F);
    float4* sf = reinterpret_cast<float4*>(&xs[0][0]);
    const int maxf4 = rows * (IN_F / 4);
    for (int i = t; i < 32 * (IN_F / 4); i += 256)
      sf[i] = (i < maxf4) ? xg[i] : make_float4(0.f, 0.f, 0.f, 0.f);
  }
  __syncthreads();
  const int ct = t & 63;   // cols ct*4 .. ct*4+3
  const int rt = t >> 6;   // rows rt*8 .. rt*8+7
  float acc[8][4];
#pragma unroll
  for (int r = 0; r < 8; r++) { acc[r][0]=0.f; acc[r][1]=0.f; acc[r][2]=0.f; acc[r][3]=0.f; }
  for (int k4 = 0; k4 < IN_F / 4; ++k4) {
    float4 xr[8];
#pragma unroll
    for (int r = 0; r < 8; r++)
      xr[r] = *reinterpret_cast<const float4*>(&xs[rt * 8 + r][k4 * 4]);
#pragma unroll
    for (int kk = 0; kk < 4; kk++) {
      const float4 w = *reinterpret_cast<const float4*>(&W1[(size_t)(k4 * 4 + kk) * 256 + ct * 4]);
#pragma unroll
      for (int r = 0; r < 8; r++) {
        const float a = reinterpret_cast<const float*>(&xr[r])[kk];
        acc[r][0] = fmaf(a, w.x, acc[r][0]);
        acc[r][1] = fmaf(a, w.y, acc[r][1]);
        acc[r][2] = fmaf(a, w.z, acc[r][2]);
        acc[r][3] = fmaf(a, w.w, acc[r][3]);
      }
    }
  }
#pragma unroll
  for (int r = 0; r < 8; r++) {
    const int row = row0 + rt * 8 + r;
    if (row < N)
      *reinterpret_cast<float4*>(&h1[(size_t)row * 256 + ct * 4]) =
          make_float4(acc[r][0], acc[r][1], acc[r][2], acc[r][3]);
  }
}

// ---------------- alpha1: per-node per-head dot with attention vectors ----------------
__global__ __launch_bounds__(256) void alpha1_kernel(
    const float* __restrict__ h1, const float* __restrict__ att_s, const float* __restrict__ att_d,
    float* __restrict__ as1, float* __restrict__ ad1, int N) {
  const int lane = threadIdx.x & 63;
  const int v = blockIdx.x * 4 + (threadIdx.x >> 6);
  if (v >= N) return;
#pragma unroll
  for (int h = 0; h < HEADS; h++) {
    const float p = h1[(size_t)v * 256 + h * 64 + lane];
    float s = p * att_s[h * 64 + lane];
    float d = p * att_d[h * 64 + lane];
#pragma unroll
    for (int o = 32; o > 0; o >>= 1) { s += __shfl_xor(s, o, 64); d += __shfl_xor(d, o, 64); }
    if (lane == 0) { as1[v * 4 + h] = s; ad1[v * 4 + h] = d; }
  }
}

// ---------------- alpha2: single head over 64 channels ----------------
__global__ __launch_bounds__(256) void alpha2_kernel(
    const float* __restrict__ h, const float* __restrict__ att_s, const float* __restrict__ att_d,
    float* __restrict__ as2, float* __restrict__ ad2, int N) {
  const int lane = threadIdx.x & 63;
  const int v = blockIdx.x * 4 + (threadIdx.x >> 6);
  if (v >= N) return;
  const float p = h[(size_t)v * 64 + lane];
  float s = p * att_s[lane];
  float d = p * att_d[lane];
#pragma unroll
  for (int o = 32; o > 0; o >>= 1) { s += __shfl_xor(s, o, 64); d += __shfl_xor(d, o, 64); }
  if (lane == 0) { as2[v] = s; ad2[v] = d; }
}

// ---------------- CSR build ----------------
__global__ __launch_bounds__(256) void hist_kernel(const int* __restrict__ dst, int* __restrict__ cnt, int E) {
  const int e = blockIdx.x * 256 + threadIdx.x;
  if (e < E) atomicAdd(&cnt[dst[e]], 1);
}

__global__ __launch_bounds__(1024) void scan_kernel(
    const int* __restrict__ cnt, int* __restrict__ row_start, int* __restrict__ cursor, int N) {
  __shared__ int part[1024];
  const int t = threadIdx.x;
  const int C = (N + 1023) / 1024;
  const int s = t * C;
  const int e = min(s + C, N);
  int sum = 0;
  for (int i = s; i < e; i++) sum += cnt[i];
  part[t] = sum;
  __syncthreads();
  for (int off = 1; off < 1024; off <<= 1) {
    int v = (t >= off) ? part[t - off] : 0;
    __syncthreads();
    part[t] += v;
    __syncthreads();
  }
  int run = (t == 0) ? 0 : part[t - 1];
  for (int i = s; i < e; i++) { row_start[i] = run; cursor[i] = run; run += cnt[i]; }
  if (t == 1023) row_start[N] = part[1023];
}

__global__ __launch_bounds__(256) void scatter_kernel(
    const int* __restrict__ src, const int* __restrict__ dst,
    int* __restrict__ cursor, int* __restrict__ csr_src, int E) {
  const int e = blockIdx.x * 256 + threadIdx.x;
  if (e < E) {
    const int d = dst[e];
    const int pos = atomicAdd(&cursor[d], 1);
    csr_src[pos] = src[e];
  }
}

// ---------------- gather1: 4-head softmax-aggregate + bias + ELU ----------------
__global__ __launch_bounds__(256) void gather1_kernel(
    const float* __restrict__ h1, const float* __restrict__ as1, const float* __restrict__ ad1,
    const float* __restrict__ b1, const int* __restrict__ row_start, const int* __restrict__ csr_src,
    float* __restrict__ hmid, int N) {
  const int lane = threadIdx.x & 63;
  const int v = blockIdx.x * 4 + (threadIdx.x >> 6);
  if (v >= N) return;
  const int rs = row_start[v], re = row_start[v + 1];
  const float4 adv = *reinterpret_cast<const float4*>(&ad1[(size_t)v * 4]);
  const float4 asv = *reinterpret_cast<const float4*>(&as1[(size_t)v * 4]);
  const float* adp = reinterpret_cast<const float*>(&adv);
  const float* asp = reinterpret_cast<const float*>(&asv);
  float eself[HEADS], m[HEADS];
#pragma unroll
  for (int h = 0; h < HEADS; h++) { eself[h] = lrelu(asp[h] + adp[h]); m[h] = eself[h]; }
  for (int k = rs; k < re; k++) {
    const int s = csr_src[k];
    const float4 av = *reinterpret_cast<const float4*>(&as1[(size_t)s * 4]);
    const float* ap = reinterpret_cast<const float*>(&av);
#pragma unroll
    for (int h = 0; h < HEADS; h++) m[h] = fmaxf(m[h], lrelu(ap[h] + adp[h]));
  }
  float acc[HEADS], den[HEADS];
#pragma unroll
  for (int h = 0; h < HEADS; h++) {
    const float w = expf(eself[h] - m[h]);
    den[h] = w;
    acc[h] = w * h1[(size_t)v * 256 + h * 64 + lane];
  }
  for (int k = rs; k < re; k++) {
    const int s = csr_src[k];
    const float4 av = *reinterpret_cast<const float4*>(&as1[(size_t)s * 4]);
    const float* ap = reinterpret_cast<const float*>(&av);
#pragma unroll
    for (int h = 0; h < HEADS; h++) {
      const float w = expf(lrelu(ap[h] + adp[h]) - m[h]);
      den[h] += w;
      acc[h] = fmaf(w, h1[(size_t)s * 256 + h * 64 + lane], acc[h]);
    }
  }
#pragma unroll
  for (int h = 0; h < HEADS; h++) {
    float o = acc[h] / (den[h] + EPS_SM) + b1[h * 64 + lane];
    hmid[(size_t)v * 256 + h * 64 + lane] = elu1(o);
  }
}

// ---------------- GEMM2: h2lin[N,64] = hmid[N,256] @ W2[256,64] ----------------
__global__ __launch_bounds__(256) void gemm2_kernel(
    const float* __restrict__ A, const float* __restrict__ W,
    float* __restrict__ Cout, int N) {
  __shared__ float as_[32][256];
  const int t = threadIdx.x;
  const int row0 = blockIdx.x * 32;
  const int rows = min(32, N - row0);
  {
    const float4* ag = reinterpret_cast<const float4*>(A + (size_t)row0 * 256);
    float4* sf = reinterpret_cast<float4*>(&as_[0][0]);
    const int maxf4 = rows * 64;
    for (int i = t; i < 32 * 64; i += 256)
      sf[i] = (i < maxf4) ? ag[i] : make_float4(0.f, 0.f, 0.f, 0.f);
  }
  __syncthreads();
  const int ct = t & 15;  // cols ct*4..+3
  const int rt = t >> 4;  // rows rt*2..+1
  float acc[2][4] = {{0.f,0.f,0.f,0.f},{0.f,0.f,0.f,0.f}};
  for (int k4 = 0; k4 < 64; ++k4) {
    const float4 xr0 = *reinterpret_cast<const float4*>(&as_[rt * 2][k4 * 4]);
    const float4 xr1 = *reinterpret_cast<const float4*>(&as_[rt * 2 + 1][k4 * 4]);
#pragma unroll
    for (int kk = 0; kk < 4; kk++) {
      const float4 w = *reinterpret_cast<const float4*>(&W[(size_t)(k4 * 4 + kk) * 64 + ct * 4]);
      const float a0 = reinterpret_cast<const float*>(&xr0)[kk];
      const float a1 = reinterpret_cast<const float*>(&xr1)[kk];
      acc[0][0] = fmaf(a0, w.x, acc[0][0]); acc[0][1] = fmaf(a0, w.y, acc[0][1]);
      acc[0][2] = fmaf(a0, w.z, acc[0][2]); acc[0][3] = fmaf(a0, w.w, acc[0][3]);
      acc[1][0] = fmaf(a1, w.x, acc[1][0]); acc[1][1] = fmaf(a1, w.y, acc[1][1]);
      acc[1][2] = fmaf(a1, w.z, acc[1][2]); acc[1][3] = fmaf(a1, w.w, acc[1][3]);
    }
  }
#pragma unroll
  for (int r = 0; r < 2; r++) {
    const int row = row0 + rt * 2 + r;
    if (row < N)
      *reinterpret_cast<float4*>(&Cout[(size_t)row * 64 + ct * 4]) =
          make_float4(acc[r][0], acc[r][1], acc[r][2], acc[r][3]);
  }
}

// ---------------- gather2: 1-head softmax-aggregate + bias + ELU ----------------
__global__ __launch_bounds__(256) void gather2_kernel(
    const float* __restrict__ hsrc, const float* __restrict__ as2, const float* __restrict__ ad2,
    const float* __restrict__ b2, const int* __restrict__ row_start, const int* __restrict__ csr_src,
    float* __restrict__ h2, int N) {
  const int lane = threadIdx.x & 63;
  const int v = blockIdx.x * 4 + (threadIdx.x >> 6);
  if (v >= N) return;
  const int rs = row_start[v], re = row_start[v + 1];
  const float adv = ad2[v];
  const float eself = lrelu(as2[v] + adv);
  float m = eself;
  for (int k = rs; k < re; k++) {
    const int s = csr_src[k];
    m = fmaxf(m, lrelu(as2[s] + adv));
  }
  float w = expf(eself - m);
  float den = w;
  float acc = w * hsrc[(size_t)v * 64 + lane];
  for (int k = rs; k < re; k++) {
    const int s = csr_src[k];
    const float ww = expf(lrelu(as2[s] + adv) - m);
    den += ww;
    acc = fmaf(ww, hsrc[(size_t)s * 64 + lane], acc);
  }
  float o = acc / (den + EPS_SM) + b2[lane];
  h2[(size_t)v * 64 + lane] = elu1(o);
}

// ---------------- mean-pool over sorted batch ----------------
__global__ __launch_bounds__(256) void pool_kernel(
    const float* __restrict__ h2, const int* __restrict__ batch,
    float* __restrict__ pooled, float* __restrict__ cntf, int N) {
  const int lane = threadIdx.x & 63;
  const int gw = blockIdx.x * 4 + (threadIdx.x >> 6);
  const int s = gw * 64;
  if (s >= N) return;
  const int e = min(s + 64, N);
  int cur = batch[s];
  float racc = 0.f;
  int rc = 0;
  for (int v = s; v < e; v++) {
    const int g = batch[v];
    if (g != cur) {
      atomicAdd(&pooled[(size_t)cur * 64 + lane], racc);
      if (lane == 0) atomicAdd(&cntf[cur], (float)rc);
      racc = 0.f; rc = 0; cur = g;
    }
    racc += h2[(size_t)v * 64 + lane];
    rc++;
  }
  atomicAdd(&pooled[(size_t)cur * 64 + lane], racc);
  if (lane == 0) atomicAdd(&cntf[cur], (float)rc);
}

// ---------------- classifier ----------------
__global__ __launch_bounds__(64) void final_kernel(
    const float* __restrict__ pooled, const float* __restrict__ cntf,
    const float* __restrict__ Wc, const float* __restrict__ bc, float* __restrict__ out) {
  const int g = threadIdx.x;
  float acc = 0.f;
  for (int c = 0; c < 64; c++) acc = fmaf(pooled[(size_t)g * 64 + c], Wc[c], acc);
  const float cnt = fmaxf(cntf[g], 1.0f);
  out[g] = acc / cnt + bc[0];
}

extern "C" void kernel_launch(void* const* d_in, const int* in_sizes, int n_in,
                              void* d_out, int out_size, void* d_ws, size_t ws_size,
                              hipStream_t stream) {
  const float* x     = (const float*)d_in[0];
  const int*   ei    = (const int*)d_in[1];
  const int*   batch = (const int*)d_in[2];
  const float* W1    = (const float*)d_in[3];
  const float* atts1 = (const float*)d_in[4];
  const float* attd1 = (const float*)d_in[5];
  const float* b1    = (const float*)d_in[6];
  const float* W2    = (const float*)d_in[7];
  const float* atts2 = (const float*)d_in[8];
  const float* attd2 = (const float*)d_in[9];
  const float* b2    = (const float*)d_in[10];
  const float* Wc    = (const float*)d_in[11];
  const float* bc    = (const float*)d_in[12];
  float* out = (float*)d_out;

  const int N = in_sizes[0] / IN_F;   // 50000
  const int E = in_sizes[1] / 2;      // 800000
  const int* src = ei;
  const int* dst = ei + E;

  char* ws = (char*)d_ws;
  size_t off = 0;
  auto take = [&](size_t bytes) -> void* {
    void* p = ws + off;
    off = (off + bytes + 255) & ~(size_t)255;
    return p;
  };
  float* h1       = (float*)take((size_t)N * 256 * sizeof(float));
  float* hmid     = (float*)take((size_t)N * 256 * sizeof(float));
  float* as1      = (float*)take((size_t)N * 4 * sizeof(float));
  float* ad1      = (float*)take((size_t)N * 4 * sizeof(float));
  float* as2      = (float*)take((size_t)N * sizeof(float));
  float* ad2      = (float*)take((size_t)N * sizeof(float));
  int*   cnt      = (int*)take((size_t)N * sizeof(int));
  int*   row_start= (int*)take((size_t)(N + 1) * sizeof(int));
  int*   cursor   = (int*)take((size_t)N * sizeof(int));
  int*   csr_src  = (int*)take((size_t)E * sizeof(int));
  float* pooled   = (float*)take((size_t)GROUPS * 64 * sizeof(float));
  float* cntf     = (float*)take((size_t)GROUPS * sizeof(float));
  // reuse of h1 buffer after gather1:
  float* h2lin = h1;                       // N x 64
  float* h2    = h1 + (size_t)N * 64;      // N x 64

  hipMemsetAsync(cnt, 0, (size_t)N * sizeof(int), stream);
  hipMemsetAsync(pooled, 0, (size_t)GROUPS * 64 * sizeof(float), stream);
  hipMemsetAsync(cntf, 0, (size_t)GROUPS * sizeof(float), stream);

  // conv1 linear + attention coefficients
  gemm1_kernel<<<(N + 31) / 32, 256, 0, stream>>>(x, W1, h1, N);
  alpha1_kernel<<<(N + 3) / 4, 256, 0, stream>>>(h1, atts1, attd1, as1, ad1, N);

  // CSR by dst
  hist_kernel<<<(E + 255) / 256, 256, 0, stream>>>(dst, cnt, E);
  scan_kernel<<<1, 1024, 0, stream>>>(cnt, row_start, cursor, N);
  scatter_kernel<<<(E + 255) / 256, 256, 0, stream>>>(src, dst, cursor, csr_src, E);

  // conv1 aggregate
  gather1_kernel<<<(N + 3) / 4, 256, 0, stream>>>(h1, as1, ad1, b1, row_start, csr_src, hmid, N);

  // conv2
  gemm2_kernel<<<(N + 31) / 32, 256, 0, stream>>>(hmid, W2, h2lin, N);
  alpha2_kernel<<<(N + 3) / 4, 256, 0, stream>>>(h2lin, atts2, attd2, as2, ad2, N);
  gather2_kernel<<<(N + 3) / 4, 256, 0, stream>>>(h2lin, as2, ad2, b2, row_start, csr_src, h2, N);

  // pooling + classifier
  pool_kernel<<<((N + 63) / 64 + 3) / 4, 256, 0, stream>>>(h2, batch, pooled, cntf, N);
  final_kernel<<<1, 64, 0, stream>>>(pooled, cntf, Wc, bc, out);

  (void)n_in; (void)out_size; (void)ws_size;
}

// Round 2
// 618.444 us; speedup vs baseline: 1.1266x; 1.1266x over previous
//
#include <hip/hip_runtime.h>
#include <hip/hip_bf16.h>

constexpr int HEADS  = 4;
constexpr int HID    = 64;
constexpr int IN_F   = 128;
constexpr int GROUPS = 64;
constexpr float NEG_SLOPE = 0.2f;
constexpr float EPS_SM    = 1e-16f;

static __device__ __forceinline__ float lrelu(float x) { return x >= 0.f ? x : NEG_SLOPE * x; }
static __device__ __forceinline__ float elu1(float x)  { return x > 0.f ? x : expm1f(x); }

// ---------------- GEMM1: h1[N,256] = x[N,128] @ W1[128,256] ----------------
__global__ __launch_bounds__(256) void gemm1_kernel(
    const float* __restrict__ x, const float* __restrict__ W1,
    float* __restrict__ h1, int N) {
  __shared__ float xs[32][IN_F];
  const int t = threadIdx.x;
  const int row0 = blockIdx.x * 32;
  const int rows = min(32, N - row0);
  {
    const float4* xg = reinterpret_cast<const float4*>(x + (size_t)row0 * IN_F);
    float4* sf = reinterpret_cast<float4*>(&xs[0][0]);
    const int maxf4 = rows * (IN_F / 4);
    for (int i = t; i < 32 * (IN_F / 4); i += 256)
      sf[i] = (i < maxf4) ? xg[i] : make_float4(0.f, 0.f, 0.f, 0.f);
  }
  __syncthreads();
  const int ct = t & 63;   // cols ct*4 .. ct*4+3
  const int rt = t >> 6;   // rows rt*8 .. rt*8+7
  float acc[8][4];
#pragma unroll
  for (int r = 0; r < 8; r++) { acc[r][0]=0.f; acc[r][1]=0.f; acc[r][2]=0.f; acc[r][3]=0.f; }
  for (int k4 = 0; k4 < IN_F / 4; ++k4) {
    float4 xr[8];
#pragma unroll
    for (int r = 0; r < 8; r++)
      xr[r] = *reinterpret_cast<const float4*>(&xs[rt * 8 + r][k4 * 4]);
#pragma unroll
    for (int kk = 0; kk < 4; kk++) {
      const float4 w = *reinterpret_cast<const float4*>(&W1[(size_t)(k4 * 4 + kk) * 256 + ct * 4]);
#pragma unroll
      for (int r = 0; r < 8; r++) {
        const float a = reinterpret_cast<const float*>(&xr[r])[kk];
        acc[r][0] = fmaf(a, w.x, acc[r][0]);
        acc[r][1] = fmaf(a, w.y, acc[r][1]);
        acc[r][2] = fmaf(a, w.z, acc[r][2]);
        acc[r][3] = fmaf(a, w.w, acc[r][3]);
      }
    }
  }
#pragma unroll
  for (int r = 0; r < 8; r++) {
    const int row = row0 + rt * 8 + r;
    if (row < N)
      *reinterpret_cast<float4*>(&h1[(size_t)row * 256 + ct * 4]) =
          make_float4(acc[r][0], acc[r][1], acc[r][2], acc[r][3]);
  }
}

// ---------------- alpha1: per-node per-head dot with attention vectors ----------------
__global__ __launch_bounds__(256) void alpha1_kernel(
    const float* __restrict__ h1, const float* __restrict__ att_s, const float* __restrict__ att_d,
    float* __restrict__ as1, float* __restrict__ ad1, int N) {
  const int lane = threadIdx.x & 63;
  const int v = blockIdx.x * 4 + (threadIdx.x >> 6);
  if (v >= N) return;
#pragma unroll
  for (int h = 0; h < HEADS; h++) {
    const float p = h1[(size_t)v * 256 + h * 64 + lane];
    float s = p * att_s[h * 64 + lane];
    float d = p * att_d[h * 64 + lane];
#pragma unroll
    for (int o = 32; o > 0; o >>= 1) { s += __shfl_xor(s, o, 64); d += __shfl_xor(d, o, 64); }
    if (lane == 0) { as1[v * 4 + h] = s; ad1[v * 4 + h] = d; }
  }
}

// ---------------- alpha2: single head over 64 channels ----------------
__global__ __launch_bounds__(256) void alpha2_kernel(
    const float* __restrict__ h, const float* __restrict__ att_s, const float* __restrict__ att_d,
    float* __restrict__ as2, float* __restrict__ ad2, int N) {
  const int lane = threadIdx.x & 63;
  const int v = blockIdx.x * 4 + (threadIdx.x >> 6);
  if (v >= N) return;
  const float p = h[(size_t)v * 64 + lane];
  float s = p * att_s[lane];
  float d = p * att_d[lane];
#pragma unroll
  for (int o = 32; o > 0; o >>= 1) { s += __shfl_xor(s, o, 64); d += __shfl_xor(d, o, 64); }
  if (lane == 0) { as2[v] = s; ad2[v] = d; }
}

// ---------------- CSR build ----------------
__global__ __launch_bounds__(256) void hist_kernel(const int* __restrict__ dst, int* __restrict__ cnt, int E) {
  const int e = blockIdx.x * 256 + threadIdx.x;
  if (e < E) atomicAdd(&cnt[dst[e]], 1);
}

__global__ __launch_bounds__(1024) void scan_kernel(
    const int* __restrict__ cnt, int* __restrict__ row_start, int* __restrict__ cursor, int N) {
  __shared__ int part[1024];
  const int t = threadIdx.x;
  const int C = (N + 1023) / 1024;
  const int s = t * C;
  const int e = min(s + C, N);
  int sum = 0;
  for (int i = s; i < e; i++) sum += cnt[i];
  part[t] = sum;
  __syncthreads();
  for (int off = 1; off < 1024; off <<= 1) {
    int v = (t >= off) ? part[t - off] : 0;
    __syncthreads();
    part[t] += v;
    __syncthreads();
  }
  int run = (t == 0) ? 0 : part[t - 1];
  for (int i = s; i < e; i++) { row_start[i] = run; cursor[i] = run; run += cnt[i]; }
  if (t == 1023) row_start[N] = part[1023];
}

__global__ __launch_bounds__(256) void scatter_kernel(
    const int* __restrict__ src, const int* __restrict__ dst,
    int* __restrict__ cursor, int* __restrict__ csr_src, int E) {
  const int e = blockIdx.x * 256 + threadIdx.x;
  if (e < E) {
    const int d = dst[e];
    const int pos = atomicAdd(&cursor[d], 1);
    csr_src[pos] = src[e];
  }
}

// ---------------- edge weights conv1: lane-parallel per-edge softmax weights ----------------
__global__ __launch_bounds__(256) void edge_w1_kernel(
    const float* __restrict__ as1, const float* __restrict__ ad1,
    const int* __restrict__ row_start, const int* __restrict__ csr_src,
    float* __restrict__ w1, float* __restrict__ wself, float* __restrict__ winv, int N) {
  const int lane = threadIdx.x & 63;
  const int v = blockIdx.x * 4 + (threadIdx.x >> 6);
  if (v >= N) return;
  const int rs = row_start[v], re = row_start[v + 1];
  const float4 adv = *reinterpret_cast<const float4*>(&ad1[(size_t)v * 4]);
  const float4 asv = *reinterpret_cast<const float4*>(&as1[(size_t)v * 4]);
  const float* adp = reinterpret_cast<const float*>(&adv);
  const float* asp = reinterpret_cast<const float*>(&asv);
  float eself[HEADS], m[HEADS];
#pragma unroll
  for (int h = 0; h < HEADS; h++) { eself[h] = lrelu(asp[h] + adp[h]); m[h] = eself[h]; }
  // pass 1: max over incoming edges, lanes strided
  for (int k = rs + lane; k < re; k += 64) {
    const int s = csr_src[k];
    const float4 av = *reinterpret_cast<const float4*>(&as1[(size_t)s * 4]);
    const float* ap = reinterpret_cast<const float*>(&av);
#pragma unroll
    for (int h = 0; h < HEADS; h++) m[h] = fmaxf(m[h], lrelu(ap[h] + adp[h]));
  }
#pragma unroll
  for (int h = 0; h < HEADS; h++)
#pragma unroll
    for (int o = 32; o > 0; o >>= 1) m[h] = fmaxf(m[h], __shfl_xor(m[h], o, 64));
  // pass 2: weights + denominator
  float den[HEADS] = {0.f, 0.f, 0.f, 0.f};
  for (int k = rs + lane; k < re; k += 64) {
    const int s = csr_src[k];
    const float4 av = *reinterpret_cast<const float4*>(&as1[(size_t)s * 4]);
    const float* ap = reinterpret_cast<const float*>(&av);
    float4 wv;
    float* wp = reinterpret_cast<float*>(&wv);
#pragma unroll
    for (int h = 0; h < HEADS; h++) {
      const float w = __expf(lrelu(ap[h] + adp[h]) - m[h]);
      wp[h] = w;
      den[h] += w;
    }
    *reinterpret_cast<float4*>(&w1[(size_t)k * 4]) = wv;
  }
#pragma unroll
  for (int h = 0; h < HEADS; h++)
#pragma unroll
    for (int o = 32; o > 0; o >>= 1) den[h] += __shfl_xor(den[h], o, 64);
  if (lane == 0) {
    float4 wsv, wiv;
    float* wsp = reinterpret_cast<float*>(&wsv);
    float* wip = reinterpret_cast<float*>(&wiv);
#pragma unroll
    for (int h = 0; h < HEADS; h++) {
      const float ws_ = __expf(eself[h] - m[h]);
      wsp[h] = ws_;
      wip[h] = 1.f / (den[h] + ws_ + EPS_SM);
    }
    *reinterpret_cast<float4*>(&wself[(size_t)v * 4]) = wsv;
    *reinterpret_cast<float4*>(&winv[(size_t)v * 4]) = wiv;
  }
}

// ---------------- edge weights conv2 (1 head) ----------------
__global__ __launch_bounds__(256) void edge_w2_kernel(
    const float* __restrict__ as2, const float* __restrict__ ad2,
    const int* __restrict__ row_start, const int* __restrict__ csr_src,
    float* __restrict__ w2, float* __restrict__ wself2, float* __restrict__ winv2, int N) {
  const int lane = threadIdx.x & 63;
  const int v = blockIdx.x * 4 + (threadIdx.x >> 6);
  if (v >= N) return;
  const int rs = row_start[v], re = row_start[v + 1];
  const float adv = ad2[v];
  const float eself = lrelu(as2[v] + adv);
  float m = eself;
  for (int k = rs + lane; k < re; k += 64)
    m = fmaxf(m, lrelu(as2[csr_src[k]] + adv));
#pragma unroll
  for (int o = 32; o > 0; o >>= 1) m = fmaxf(m, __shfl_xor(m, o, 64));
  float den = 0.f;
  for (int k = rs + lane; k < re; k += 64) {
    const float w = __expf(lrelu(as2[csr_src[k]] + adv) - m);
    w2[k] = w;
    den += w;
  }
#pragma unroll
  for (int o = 32; o > 0; o >>= 1) den += __shfl_xor(den, o, 64);
  if (lane == 0) {
    const float ws_ = __expf(eself - m);
    wself2[v] = ws_;
    winv2[v] = 1.f / (den + ws_ + EPS_SM);
  }
}

// ---------------- gather1: pure weighted gather + bias + ELU ----------------
__global__ __launch_bounds__(256) void gather1w_kernel(
    const float* __restrict__ h1, const float* __restrict__ w1,
    const float* __restrict__ wself, const float* __restrict__ winv,
    const float* __restrict__ b1, const int* __restrict__ row_start,
    const int* __restrict__ csr_src, float* __restrict__ hmid, int N) {
  const int lane = threadIdx.x & 63;
  const int v = blockIdx.x * 4 + (threadIdx.x >> 6);
  if (v >= N) return;
  const int rs = row_start[v], re = row_start[v + 1];
  const float4 wsv = *reinterpret_cast<const float4*>(&wself[(size_t)v * 4]);
  const float4 wiv = *reinterpret_cast<const float4*>(&winv[(size_t)v * 4]);
  const float* wsp = reinterpret_cast<const float*>(&wsv);
  const float* wip = reinterpret_cast<const float*>(&wiv);
  const float* hv = h1 + (size_t)v * 256;
  float acc[HEADS];
#pragma unroll
  for (int h = 0; h < HEADS; h++) acc[h] = wsp[h] * hv[h * 64 + lane];
  if (rs < re) {
    int sN = csr_src[rs];
    float4 wN = *reinterpret_cast<const float4*>(&w1[(size_t)rs * 4]);
    for (int k = rs; k < re; ++k) {
      const int s = sN;
      const float4 wv = wN;
      const float* wp = reinterpret_cast<const float*>(&wv);
      const int kn = (k + 1 < re) ? k + 1 : k;
      sN = csr_src[kn];
      wN = *reinterpret_cast<const float4*>(&w1[(size_t)kn * 4]);
      const float* hs = h1 + (size_t)s * 256;
#pragma unroll
      for (int h = 0; h < HEADS; h++)
        acc[h] = fmaf(wp[h], hs[h * 64 + lane], acc[h]);
    }
  }
#pragma unroll
  for (int h = 0; h < HEADS; h++) {
    const float o = acc[h] * wip[h] + b1[h * 64 + lane];
    hmid[(size_t)v * 256 + h * 64 + lane] = elu1(o);
  }
}

// ---------------- gather2: pure weighted gather + bias + ELU (1 head) ----------------
__global__ __launch_bounds__(256) void gather2w_kernel(
    const float* __restrict__ hsrc, const float* __restrict__ w2,
    const float* __restrict__ wself2, const float* __restrict__ winv2,
    const float* __restrict__ b2, const int* __restrict__ row_start,
    const int* __restrict__ csr_src, float* __restrict__ h2, int N) {
  const int lane = threadIdx.x & 63;
  const int v = blockIdx.x * 4 + (threadIdx.x >> 6);
  if (v >= N) return;
  const int rs = row_start[v], re = row_start[v + 1];
  float acc = wself2[v] * hsrc[(size_t)v * 64 + lane];
  if (rs < re) {
    int sN = csr_src[rs];
    float wN = w2[rs];
    for (int k = rs; k < re; ++k) {
      const int s = sN;
      const float w = wN;
      const int kn = (k + 1 < re) ? k + 1 : k;
      sN = csr_src[kn];
      wN = w2[kn];
      acc = fmaf(w, hsrc[(size_t)s * 64 + lane], acc);
    }
  }
  const float o = acc * winv2[v] + b2[lane];
  h2[(size_t)v * 64 + lane] = elu1(o);
}

// ---------------- mean-pool over sorted batch ----------------
__global__ __launch_bounds__(256) void pool_kernel(
    const float* __restrict__ h2, const int* __restrict__ batch,
    float* __restrict__ pooled, float* __restrict__ cntf, int N) {
  const int lane = threadIdx.x & 63;
  const int gw = blockIdx.x * 4 + (threadIdx.x >> 6);
  const int s = gw * 64;
  if (s >= N) return;
  const int e = min(s + 64, N);
  int cur = batch[s];
  float racc = 0.f;
  int rc = 0;
  for (int v = s; v < e; v++) {
    const int g = batch[v];
    if (g != cur) {
      atomicAdd(&pooled[(size_t)cur * 64 + lane], racc);
      if (lane == 0) atomicAdd(&cntf[cur], (float)rc);
      racc = 0.f; rc = 0; cur = g;
    }
    racc += h2[(size_t)v * 64 + lane];
    rc++;
  }
  atomicAdd(&pooled[(size_t)cur * 64 + lane], racc);
  if (lane == 0) atomicAdd(&cntf[cur], (float)rc);
}

// ---------------- classifier ----------------
__global__ __launch_bounds__(64) void final_kernel(
    const float* __restrict__ pooled, const float* __restrict__ cntf,
    const float* __restrict__ Wc, const float* __restrict__ bc, float* __restrict__ out) {
  const int g = threadIdx.x;
  float acc = 0.f;
  for (int c = 0; c < 64; c++) acc = fmaf(pooled[(size_t)g * 64 + c], Wc[c], acc);
  const float cnt = fmaxf(cntf[g], 1.0f);
  out[g] = acc / cnt + bc[0];
}

// ---------------- GEMM2: h2lin[N,64] = hmid[N,256] @ W2[256,64] ----------------
__global__ __launch_bounds__(256) void gemm2_kernel(
    const float* __restrict__ A, const float* __restrict__ W,
    float* __restrict__ Cout, int N) {
  __shared__ float as_[32][256];
  const int t = threadIdx.x;
  const int row0 = blockIdx.x * 32;
  const int rows = min(32, N - row0);
  {
    const float4* ag = reinterpret_cast<const float4*>(A + (size_t)row0 * 256);
    float4* sf = reinterpret_cast<float4*>(&as_[0][0]);
    const int maxf4 = rows * 64;
    for (int i = t; i < 32 * 64; i += 256)
      sf[i] = (i < maxf4) ? ag[i] : make_float4(0.f, 0.f, 0.f, 0.f);
  }
  __syncthreads();
  const int ct = t & 15;  // cols ct*4..+3
  const int rt = t >> 4;  // rows rt*2..+1
  float acc[2][4] = {{0.f,0.f,0.f,0.f},{0.f,0.f,0.f,0.f}};
  for (int k4 = 0; k4 < 64; ++k4) {
    const float4 xr0 = *reinterpret_cast<const float4*>(&as_[rt * 2][k4 * 4]);
    const float4 xr1 = *reinterpret_cast<const float4*>(&as_[rt * 2 + 1][k4 * 4]);
#pragma unroll
    for (int kk = 0; kk < 4; kk++) {
      const float4 w = *reinterpret_cast<const float4*>(&W[(size_t)(k4 * 4 + kk) * 64 + ct * 4]);
      const float a0 = reinterpret_cast<const float*>(&xr0)[kk];
      const float a1 = reinterpret_cast<const float*>(&xr1)[kk];
      acc[0][0] = fmaf(a0, w.x, acc[0][0]); acc[0][1] = fmaf(a0, w.y, acc[0][1]);
      acc[0][2] = fmaf(a0, w.z, acc[0][2]); acc[0][3] = fmaf(a0, w.w, acc[0][3]);
      acc[1][0] = fmaf(a1, w.x, acc[1][0]); acc[1][1] = fmaf(a1, w.y, acc[1][1]);
      acc[1][2] = fmaf(a1, w.z, acc[1][2]); acc[1][3] = fmaf(a1, w.w, acc[1][3]);
    }
  }
#pragma unroll
  for (int r = 0; r < 2; r++) {
    const int row = row0 + rt * 2 + r;
    if (row < N)
      *reinterpret_cast<float4*>(&Cout[(size_t)row * 64 + ct * 4]) =
          make_float4(acc[r][0], acc[r][1], acc[r][2], acc[r][3]);
  }
}

extern "C" void kernel_launch(void* const* d_in, const int* in_sizes, int n_in,
                              void* d_out, int out_size, void* d_ws, size_t ws_size,
                              hipStream_t stream) {
  const float* x     = (const float*)d_in[0];
  const int*   ei    = (const int*)d_in[1];
  const int*   batch = (const int*)d_in[2];
  const float* W1    = (const float*)d_in[3];
  const float* atts1 = (const float*)d_in[4];
  const float* attd1 = (const float*)d_in[5];
  const float* b1    = (const float*)d_in[6];
  const float* W2    = (const float*)d_in[7];
  const float* atts2 = (const float*)d_in[8];
  const float* attd2 = (const float*)d_in[9];
  const float* b2    = (const float*)d_in[10];
  const float* Wc    = (const float*)d_in[11];
  const float* bc    = (const float*)d_in[12];
  float* out = (float*)d_out;

  const int N = in_sizes[0] / IN_F;   // 50000
  const int E = in_sizes[1] / 2;      // 800000
  const int* src = ei;
  const int* dst = ei + E;

  char* ws = (char*)d_ws;
  size_t off = 0;
  auto take = [&](size_t bytes) -> void* {
    void* p = ws + off;
    off = (off + bytes + 255) & ~(size_t)255;
    return p;
  };
  float* h1       = (float*)take((size_t)N * 256 * sizeof(float));
  float* hmid     = (float*)take((size_t)N * 256 * sizeof(float));
  float* as1      = (float*)take((size_t)N * 4 * sizeof(float));
  float* ad1      = (float*)take((size_t)N * 4 * sizeof(float));
  float* as2      = (float*)take((size_t)N * sizeof(float));
  float* ad2      = (float*)take((size_t)N * sizeof(float));
  int*   cnt      = (int*)take((size_t)N * sizeof(int));
  int*   row_start= (int*)take((size_t)(N + 1) * sizeof(int));
  int*   cursor   = (int*)take((size_t)N * sizeof(int));
  int*   csr_src  = (int*)take((size_t)E * sizeof(int));
  float* pooled   = (float*)take((size_t)GROUPS * 64 * sizeof(float));
  float* cntf     = (float*)take((size_t)GROUPS * sizeof(float));
  float* w1       = (float*)take((size_t)E * 4 * sizeof(float));   // per-edge conv1 weights
  float* wself1   = (float*)take((size_t)N * 4 * sizeof(float));
  float* winv1    = (float*)take((size_t)N * 4 * sizeof(float));
  // conv2 edge buffers alias conv1's (w1 dead after gather1w)
  float* w2     = w1;          // N.B. E floats
  float* wself2 = wself1;
  float* winv2  = winv1;
  // reuse of h1 buffer after gather1:
  float* h2lin = h1;                       // N x 64
  float* h2    = h1 + (size_t)N * 64;      // N x 64

  hipMemsetAsync(cnt, 0, (size_t)N * sizeof(int), stream);
  hipMemsetAsync(pooled, 0, (size_t)GROUPS * 64 * sizeof(float), stream);
  hipMemsetAsync(cntf, 0, (size_t)GROUPS * sizeof(float), stream);

  // conv1 linear + attention coefficients
  gemm1_kernel<<<(N + 31) / 32, 256, 0, stream>>>(x, W1, h1, N);
  alpha1_kernel<<<(N + 3) / 4, 256, 0, stream>>>(h1, atts1, attd1, as1, ad1, N);

  // CSR by dst
  hist_kernel<<<(E + 255) / 256, 256, 0, stream>>>(dst, cnt, E);
  scan_kernel<<<1, 1024, 0, stream>>>(cnt, row_start, cursor, N);
  scatter_kernel<<<(E + 255) / 256, 256, 0, stream>>>(src, dst, cursor, csr_src, E);

  // conv1: edge weights then pure gather
  edge_w1_kernel<<<(N + 3) / 4, 256, 0, stream>>>(as1, ad1, row_start, csr_src, w1, wself1, winv1, N);
  gather1w_kernel<<<(N + 3) / 4, 256, 0, stream>>>(h1, w1, wself1, winv1, b1, row_start, csr_src, hmid, N);

  // conv2
  gemm2_kernel<<<(N + 31) / 32, 256, 0, stream>>>(hmid, W2, h2lin, N);
  alpha2_kernel<<<(N + 3) / 4, 256, 0, stream>>>(h2lin, atts2, attd2, as2, ad2, N);
  edge_w2_kernel<<<(N + 3) / 4, 256, 0, stream>>>(as2, ad2, row_start, csr_src, w2, wself2, winv2, N);
  gather2w_kernel<<<(N + 3) / 4, 256, 0, stream>>>(h2lin, w2, wself2, winv2, b2, row_start, csr_src, h2, N);

  // pooling + classifier
  pool_kernel<<<((N + 63) / 64 + 3) / 4, 256, 0, stream>>>(h2, batch, pooled, cntf, N);
  final_kernel<<<1, 64, 0, stream>>>(pooled, cntf, Wc, bc, out);

  (void)n_in; (void)out_size; (void)ws_size;
}

// Round 3
// 529.794 us; speedup vs baseline: 1.3151x; 1.1673x over previous
//
#include <hip/hip_runtime.h>
#include <hip/hip_bf16.h>

constexpr int HEADS  = 4;
constexpr int HID    = 64;
constexpr int IN_F   = 128;
constexpr int GROUPS = 64;
constexpr float NEG_SLOPE = 0.2f;
constexpr float EPS_SM    = 1e-16f;

static __device__ __forceinline__ float lrelu(float x) { return x >= 0.f ? x : NEG_SLOPE * x; }
static __device__ __forceinline__ float elu1(float x)  { return x > 0.f ? x : expm1f(x); }

static __device__ __forceinline__ float bf2f(unsigned int u) {
  union { unsigned int i; float f; } x; x.i = u << 16; return x.f;
}
static __device__ __forceinline__ unsigned short f2bf(float f) {
  union { float f; unsigned int i; } x; x.f = f;
  unsigned int lsb = (x.i >> 16) & 1u;
  x.i += 0x7fffu + lsb;
  return (unsigned short)(x.i >> 16);
}

// ---- GEMM1 + fused alpha1: h1b[N,256](bf16) = x @ W1 ; as1/ad1[N,4] ----
__global__ __launch_bounds__(256) void gemm1_kernel(
    const float* __restrict__ x, const float* __restrict__ W1,
    const float* __restrict__ att_s, const float* __restrict__ att_d,
    unsigned short* __restrict__ h1b, float* __restrict__ as1, float* __restrict__ ad1, int N) {
  __shared__ float xs[32][IN_F];
  const int t = threadIdx.x;
  const int row0 = blockIdx.x * 32;
  const int rows = min(32, N - row0);
  {
    const float4* xg = reinterpret_cast<const float4*>(x + (size_t)row0 * IN_F);
    float4* sf = reinterpret_cast<float4*>(&xs[0][0]);
    const int maxf4 = rows * (IN_F / 4);
    for (int i = t; i < 32 * (IN_F / 4); i += 256)
      sf[i] = (i < maxf4) ? xg[i] : make_float4(0.f, 0.f, 0.f, 0.f);
  }
  __syncthreads();
  const int ct = t & 63;   // cols ct*4 .. ct*4+3
  const int rt = t >> 6;   // wave id; rows rt*8 .. rt*8+7
  float acc[8][4];
#pragma unroll
  for (int r = 0; r < 8; r++) { acc[r][0]=0.f; acc[r][1]=0.f; acc[r][2]=0.f; acc[r][3]=0.f; }
  for (int k4 = 0; k4 < IN_F / 4; ++k4) {
    float4 xr[8];
#pragma unroll
    for (int r = 0; r < 8; r++)
      xr[r] = *reinterpret_cast<const float4*>(&xs[rt * 8 + r][k4 * 4]);
#pragma unroll
    for (int kk = 0; kk < 4; kk++) {
      const float4 w = *reinterpret_cast<const float4*>(&W1[(size_t)(k4 * 4 + kk) * 256 + ct * 4]);
#pragma unroll
      for (int r = 0; r < 8; r++) {
        const float a = reinterpret_cast<const float*>(&xr[r])[kk];
        acc[r][0] = fmaf(a, w.x, acc[r][0]);
        acc[r][1] = fmaf(a, w.y, acc[r][1]);
        acc[r][2] = fmaf(a, w.z, acc[r][2]);
        acc[r][3] = fmaf(a, w.w, acc[r][3]);
      }
    }
  }
  // fused alpha: per-row dots with att vectors, reduced over each head's 16 lanes
  const float4 avs = *reinterpret_cast<const float4*>(&att_s[ct * 4]);
  const float4 avd = *reinterpret_cast<const float4*>(&att_d[ct * 4]);
  float ps[8], pd[8];
#pragma unroll
  for (int r = 0; r < 8; r++) {
    ps[r] = acc[r][0]*avs.x + acc[r][1]*avs.y + acc[r][2]*avs.z + acc[r][3]*avs.w;
    pd[r] = acc[r][0]*avd.x + acc[r][1]*avd.y + acc[r][2]*avd.z + acc[r][3]*avd.w;
#pragma unroll
    for (int o = 8; o > 0; o >>= 1) {
      ps[r] += __shfl_xor(ps[r], o, 64);
      pd[r] += __shfl_xor(pd[r], o, 64);
    }
  }
  if ((ct & 15) == 0) {
    const int h = ct >> 4;
#pragma unroll
    for (int r = 0; r < 8; r++) {
      const int row = row0 + rt * 8 + r;
      if (row < N) { as1[(size_t)row * 4 + h] = ps[r]; ad1[(size_t)row * 4 + h] = pd[r]; }
    }
  }
  // bf16 store
#pragma unroll
  for (int r = 0; r < 8; r++) {
    const int row = row0 + rt * 8 + r;
    if (row < N) {
      ushort4 ov;
      ov.x = f2bf(acc[r][0]); ov.y = f2bf(acc[r][1]);
      ov.z = f2bf(acc[r][2]); ov.w = f2bf(acc[r][3]);
      reinterpret_cast<ushort4*>(h1b + (size_t)row * 256)[ct] = ov;
    }
  }
}

// ---------------- CSR build ----------------
__global__ __launch_bounds__(256) void hist_kernel(const int* __restrict__ dst, int* __restrict__ cnt, int E) {
  const int e = blockIdx.x * 256 + threadIdx.x;
  if (e < E) atomicAdd(&cnt[dst[e]], 1);
}

__global__ __launch_bounds__(1024) void scan_kernel(
    const int* __restrict__ cnt, int* __restrict__ row_start, int* __restrict__ cursor, int N) {
  __shared__ int part[1024];
  const int t = threadIdx.x;
  const int C = (N + 1023) / 1024;
  const int s = t * C;
  const int e = min(s + C, N);
  int sum = 0;
  for (int i = s; i < e; i++) sum += cnt[i];
  part[t] = sum;
  __syncthreads();
  for (int off = 1; off < 1024; off <<= 1) {
    int v = (t >= off) ? part[t - off] : 0;
    __syncthreads();
    part[t] += v;
    __syncthreads();
  }
  int run = (t == 0) ? 0 : part[t - 1];
  for (int i = s; i < e; i++) { row_start[i] = run; cursor[i] = run; run += cnt[i]; }
  if (t == 1023) row_start[N] = part[1023];
}

__global__ __launch_bounds__(256) void scatter_kernel(
    const int* __restrict__ src, const int* __restrict__ dst,
    int* __restrict__ cursor, int* __restrict__ csr_src, int E) {
  const int e = blockIdx.x * 256 + threadIdx.x;
  if (e < E) {
    const int d = dst[e];
    const int pos = atomicAdd(&cursor[d], 1);
    csr_src[pos] = src[e];
  }
}

// ---------------- edge weights conv1 ----------------
__global__ __launch_bounds__(256) void edge_w1_kernel(
    const float* __restrict__ as1, const float* __restrict__ ad1,
    const int* __restrict__ row_start, const int* __restrict__ csr_src,
    float* __restrict__ w1, float* __restrict__ wself, float* __restrict__ winv, int N) {
  const int lane = threadIdx.x & 63;
  const int v = blockIdx.x * 4 + (threadIdx.x >> 6);
  if (v >= N) return;
  const int rs = row_start[v], re = row_start[v + 1];
  const float4 adv = *reinterpret_cast<const float4*>(&ad1[(size_t)v * 4]);
  const float4 asv = *reinterpret_cast<const float4*>(&as1[(size_t)v * 4]);
  const float* adp = reinterpret_cast<const float*>(&adv);
  const float* asp = reinterpret_cast<const float*>(&asv);
  float eself[HEADS], m[HEADS];
#pragma unroll
  for (int h = 0; h < HEADS; h++) { eself[h] = lrelu(asp[h] + adp[h]); m[h] = eself[h]; }
  for (int k = rs + lane; k < re; k += 64) {
    const int s = csr_src[k];
    const float4 av = *reinterpret_cast<const float4*>(&as1[(size_t)s * 4]);
    const float* ap = reinterpret_cast<const float*>(&av);
#pragma unroll
    for (int h = 0; h < HEADS; h++) m[h] = fmaxf(m[h], lrelu(ap[h] + adp[h]));
  }
#pragma unroll
  for (int h = 0; h < HEADS; h++)
#pragma unroll
    for (int o = 32; o > 0; o >>= 1) m[h] = fmaxf(m[h], __shfl_xor(m[h], o, 64));
  float den[HEADS] = {0.f, 0.f, 0.f, 0.f};
  for (int k = rs + lane; k < re; k += 64) {
    const int s = csr_src[k];
    const float4 av = *reinterpret_cast<const float4*>(&as1[(size_t)s * 4]);
    const float* ap = reinterpret_cast<const float*>(&av);
    float4 wv;
    float* wp = reinterpret_cast<float*>(&wv);
#pragma unroll
    for (int h = 0; h < HEADS; h++) {
      const float w = __expf(lrelu(ap[h] + adp[h]) - m[h]);
      wp[h] = w;
      den[h] += w;
    }
    *reinterpret_cast<float4*>(&w1[(size_t)k * 4]) = wv;
  }
#pragma unroll
  for (int h = 0; h < HEADS; h++)
#pragma unroll
    for (int o = 32; o > 0; o >>= 1) den[h] += __shfl_xor(den[h], o, 64);
  if (lane == 0) {
    float4 wsv, wiv;
    float* wsp = reinterpret_cast<float*>(&wsv);
    float* wip = reinterpret_cast<float*>(&wiv);
#pragma unroll
    for (int h = 0; h < HEADS; h++) {
      const float ws_ = __expf(eself[h] - m[h]);
      wsp[h] = ws_;
      wip[h] = 1.f / (den[h] + ws_ + EPS_SM);
    }
    *reinterpret_cast<float4*>(&wself[(size_t)v * 4]) = wsv;
    *reinterpret_cast<float4*>(&winv[(size_t)v * 4]) = wiv;
  }
}

// ---------------- edge weights conv2 (1 head) ----------------
__global__ __launch_bounds__(256) void edge_w2_kernel(
    const float* __restrict__ as2, const float* __restrict__ ad2,
    const int* __restrict__ row_start, const int* __restrict__ csr_src,
    float* __restrict__ w2, float* __restrict__ wself2, float* __restrict__ winv2, int N) {
  const int lane = threadIdx.x & 63;
  const int v = blockIdx.x * 4 + (threadIdx.x >> 6);
  if (v >= N) return;
  const int rs = row_start[v], re = row_start[v + 1];
  const float adv = ad2[v];
  const float eself = lrelu(as2[v] + adv);
  float m = eself;
  for (int k = rs + lane; k < re; k += 64)
    m = fmaxf(m, lrelu(as2[csr_src[k]] + adv));
#pragma unroll
  for (int o = 32; o > 0; o >>= 1) m = fmaxf(m, __shfl_xor(m, o, 64));
  float den = 0.f;
  for (int k = rs + lane; k < re; k += 64) {
    const float w = __expf(lrelu(as2[csr_src[k]] + adv) - m);
    w2[k] = w;
    den += w;
  }
#pragma unroll
  for (int o = 32; o > 0; o >>= 1) den += __shfl_xor(den, o, 64);
  if (lane == 0) {
    const float ws_ = __expf(eself - m);
    wself2[v] = ws_;
    winv2[v] = 1.f / (den + ws_ + EPS_SM);
  }
}

// ---- gather1: bf16 gather, ushort4/lane covers all 4 heads in one transaction ----
__global__ __launch_bounds__(256) void gather1w_kernel(
    const unsigned short* __restrict__ h1b, const float* __restrict__ w1,
    const float* __restrict__ wself, const float* __restrict__ winv,
    const float* __restrict__ b1, const int* __restrict__ row_start,
    const int* __restrict__ csr_src, unsigned short* __restrict__ hmidb, int N) {
  const int lane = threadIdx.x & 63;
  const int v = blockIdx.x * 4 + (threadIdx.x >> 6);
  if (v >= N) return;
  const int hd = lane >> 4;       // head of this lane's 4 channels
  const int rs = row_start[v], re = row_start[v + 1];
  const float ws = wself[(size_t)v * 4 + hd];
  const ushort4 sv = reinterpret_cast<const ushort4*>(h1b + (size_t)v * 256)[lane];
  float4 acc;
  acc.x = ws * bf2f(sv.x); acc.y = ws * bf2f(sv.y);
  acc.z = ws * bf2f(sv.z); acc.w = ws * bf2f(sv.w);
  if (rs < re) {
    int sN = csr_src[rs];
    float wN = w1[(size_t)rs * 4 + hd];
    for (int k = rs; k < re; ++k) {
      const int s = sN;
      const float w = wN;
      const int kn = (k + 1 < re) ? k + 1 : k;
      sN = csr_src[kn];
      wN = w1[(size_t)kn * 4 + hd];
      const ushort4 f = reinterpret_cast<const ushort4*>(h1b + (size_t)s * 256)[lane];
      acc.x = fmaf(w, bf2f(f.x), acc.x);
      acc.y = fmaf(w, bf2f(f.y), acc.y);
      acc.z = fmaf(w, bf2f(f.z), acc.z);
      acc.w = fmaf(w, bf2f(f.w), acc.w);
    }
  }
  const float wi = winv[(size_t)v * 4 + hd];
  const int c0 = lane * 4;
  const float4 bv = *reinterpret_cast<const float4*>(&b1[c0]);
  ushort4 ov;
  ov.x = f2bf(elu1(acc.x * wi + bv.x));
  ov.y = f2bf(elu1(acc.y * wi + bv.y));
  ov.z = f2bf(elu1(acc.z * wi + bv.z));
  ov.w = f2bf(elu1(acc.w * wi + bv.w));
  reinterpret_cast<ushort4*>(hmidb + (size_t)v * 256)[lane] = ov;
}

// ---- GEMM2 + fused alpha2: h2b[N,64](bf16) = hmidb @ W2 ; as2/ad2[N] ----
__global__ __launch_bounds__(256) void gemm2_kernel(
    const unsigned short* __restrict__ A, const float* __restrict__ W,
    const float* __restrict__ att_s, const float* __restrict__ att_d,
    unsigned short* __restrict__ h2b, float* __restrict__ as2, float* __restrict__ ad2, int N) {
  __shared__ float as_[32][256];
  const int t = threadIdx.x;
  const int row0 = blockIdx.x * 32;
  const int rows = min(32, N - row0);
  {
    const uint4* ag = reinterpret_cast<const uint4*>(A + (size_t)row0 * 256);
    const int maxu4 = rows * 32;
    for (int i = t; i < 32 * 32; i += 256) {
      uint4 u = (i < maxu4) ? ag[i] : make_uint4(0u, 0u, 0u, 0u);
      float* dp = &as_[i >> 5][(i & 31) * 8];
      dp[0] = bf2f(u.x & 0xffffu); dp[1] = bf2f(u.x >> 16);
      dp[2] = bf2f(u.y & 0xffffu); dp[3] = bf2f(u.y >> 16);
      dp[4] = bf2f(u.z & 0xffffu); dp[5] = bf2f(u.z >> 16);
      dp[6] = bf2f(u.w & 0xffffu); dp[7] = bf2f(u.w >> 16);
    }
  }
  __syncthreads();
  const int ct = t & 15;  // cols ct*4..+3
  const int rt = t >> 4;  // rows rt*2..+1
  float acc[2][4] = {{0.f,0.f,0.f,0.f},{0.f,0.f,0.f,0.f}};
  for (int k4 = 0; k4 < 64; ++k4) {
    const float4 xr0 = *reinterpret_cast<const float4*>(&as_[rt * 2][k4 * 4]);
    const float4 xr1 = *reinterpret_cast<const float4*>(&as_[rt * 2 + 1][k4 * 4]);
#pragma unroll
    for (int kk = 0; kk < 4; kk++) {
      const float4 w = *reinterpret_cast<const float4*>(&W[(size_t)(k4 * 4 + kk) * 64 + ct * 4]);
      const float a0 = reinterpret_cast<const float*>(&xr0)[kk];
      const float a1 = reinterpret_cast<const float*>(&xr1)[kk];
      acc[0][0] = fmaf(a0, w.x, acc[0][0]); acc[0][1] = fmaf(a0, w.y, acc[0][1]);
      acc[0][2] = fmaf(a0, w.z, acc[0][2]); acc[0][3] = fmaf(a0, w.w, acc[0][3]);
      acc[1][0] = fmaf(a1, w.x, acc[1][0]); acc[1][1] = fmaf(a1, w.y, acc[1][1]);
      acc[1][2] = fmaf(a1, w.z, acc[1][2]); acc[1][3] = fmaf(a1, w.w, acc[1][3]);
    }
  }
  // fused alpha2: dot over 64 cols, reduce across the 16 ct lanes
  const float4 avs = *reinterpret_cast<const float4*>(&att_s[ct * 4]);
  const float4 avd = *reinterpret_cast<const float4*>(&att_d[ct * 4]);
  float ps[2], pd[2];
#pragma unroll
  for (int r = 0; r < 2; r++) {
    ps[r] = acc[r][0]*avs.x + acc[r][1]*avs.y + acc[r][2]*avs.z + acc[r][3]*avs.w;
    pd[r] = acc[r][0]*avd.x + acc[r][1]*avd.y + acc[r][2]*avd.z + acc[r][3]*avd.w;
#pragma unroll
    for (int o = 8; o > 0; o >>= 1) {
      ps[r] += __shfl_xor(ps[r], o, 64);
      pd[r] += __shfl_xor(pd[r], o, 64);
    }
  }
  if (((t & 63) & 15) == 0) {
#pragma unroll
    for (int r = 0; r < 2; r++) {
      const int row = row0 + rt * 2 + r;
      if (row < N) { as2[row] = ps[r]; ad2[row] = pd[r]; }
    }
  }
#pragma unroll
  for (int r = 0; r < 2; r++) {
    const int row = row0 + rt * 2 + r;
    if (row < N) {
      ushort4 ov;
      ov.x = f2bf(acc[r][0]); ov.y = f2bf(acc[r][1]);
      ov.z = f2bf(acc[r][2]); ov.w = f2bf(acc[r][3]);
      reinterpret_cast<ushort4*>(h2b + (size_t)row * 64)[ct] = ov;
    }
  }
}

// ---- gather2: bf16, 2 edges per wave iteration ----
__global__ __launch_bounds__(256) void gather2w_kernel(
    const unsigned short* __restrict__ h2b, const float* __restrict__ w2,
    const float* __restrict__ wself2, const float* __restrict__ winv2,
    const float* __restrict__ b2, const int* __restrict__ row_start,
    const int* __restrict__ csr_src, float* __restrict__ h2, int N) {
  const int lane = threadIdx.x & 63;
  const int v = blockIdx.x * 4 + (threadIdx.x >> 6);
  if (v >= N) return;
  const int half = lane >> 5;   // 0/1: which edge of the pair
  const int cl = lane & 31;     // channels 2cl, 2cl+1
  const int rs = row_start[v], re = row_start[v + 1];
  float ax = 0.f, ay = 0.f;
  if (half == 0) {
    const unsigned int u = reinterpret_cast<const unsigned int*>(h2b + (size_t)v * 64)[cl];
    const float ws = wself2[v];
    ax = ws * bf2f(u & 0xffffu);
    ay = ws * bf2f(u >> 16);
  }
  for (int k = rs + half; k < re; k += 2) {
    const int s = csr_src[k];
    const float w = w2[k];
    const unsigned int u = reinterpret_cast<const unsigned int*>(h2b + (size_t)s * 64)[cl];
    ax = fmaf(w, bf2f(u & 0xffffu), ax);
    ay = fmaf(w, bf2f(u >> 16), ay);
  }
  ax += __shfl_xor(ax, 32, 64);
  ay += __shfl_xor(ay, 32, 64);
  if (half == 0) {
    const float wi = winv2[v];
    float2 o;
    o.x = elu1(ax * wi + b2[2 * cl]);
    o.y = elu1(ay * wi + b2[2 * cl + 1]);
    reinterpret_cast<float2*>(h2 + (size_t)v * 64)[cl] = o;
  }
}

// ---------------- mean-pool over sorted batch ----------------
__global__ __launch_bounds__(256) void pool_kernel(
    const float* __restrict__ h2, const int* __restrict__ batch,
    float* __restrict__ pooled, float* __restrict__ cntf, int N) {
  const int lane = threadIdx.x & 63;
  const int gw = blockIdx.x * 4 + (threadIdx.x >> 6);
  const int s = gw * 64;
  if (s >= N) return;
  const int e = min(s + 64, N);
  int cur = batch[s];
  float racc = 0.f;
  int rc = 0;
  for (int v = s; v < e; v++) {
    const int g = batch[v];
    if (g != cur) {
      atomicAdd(&pooled[(size_t)cur * 64 + lane], racc);
      if (lane == 0) atomicAdd(&cntf[cur], (float)rc);
      racc = 0.f; rc = 0; cur = g;
    }
    racc += h2[(size_t)v * 64 + lane];
    rc++;
  }
  atomicAdd(&pooled[(size_t)cur * 64 + lane], racc);
  if (lane == 0) atomicAdd(&cntf[cur], (float)rc);
}

// ---------------- classifier ----------------
__global__ __launch_bounds__(64) void final_kernel(
    const float* __restrict__ pooled, const float* __restrict__ cntf,
    const float* __restrict__ Wc, const float* __restrict__ bc, float* __restrict__ out) {
  const int g = threadIdx.x;
  float acc = 0.f;
  for (int c = 0; c < 64; c++) acc = fmaf(pooled[(size_t)g * 64 + c], Wc[c], acc);
  const float cnt = fmaxf(cntf[g], 1.0f);
  out[g] = acc / cnt + bc[0];
}

extern "C" void kernel_launch(void* const* d_in, const int* in_sizes, int n_in,
                              void* d_out, int out_size, void* d_ws, size_t ws_size,
                              hipStream_t stream) {
  const float* x     = (const float*)d_in[0];
  const int*   ei    = (const int*)d_in[1];
  const int*   batch = (const int*)d_in[2];
  const float* W1    = (const float*)d_in[3];
  const float* atts1 = (const float*)d_in[4];
  const float* attd1 = (const float*)d_in[5];
  const float* b1    = (const float*)d_in[6];
  const float* W2    = (const float*)d_in[7];
  const float* atts2 = (const float*)d_in[8];
  const float* attd2 = (const float*)d_in[9];
  const float* b2    = (const float*)d_in[10];
  const float* Wc    = (const float*)d_in[11];
  const float* bc    = (const float*)d_in[12];
  float* out = (float*)d_out;

  const int N = in_sizes[0] / IN_F;   // 50000
  const int E = in_sizes[1] / 2;      // 800000
  const int* src = ei;
  const int* dst = ei + E;

  char* ws = (char*)d_ws;
  size_t off = 0;
  auto take = [&](size_t bytes) -> void* {
    void* p = ws + off;
    off = (off + bytes + 255) & ~(size_t)255;
    return p;
  };
  unsigned short* h1b   = (unsigned short*)take((size_t)N * 256 * 2);
  unsigned short* hmidb = (unsigned short*)take((size_t)N * 256 * 2);
  unsigned short* h2b   = (unsigned short*)take((size_t)N * 64 * 2);
  float* as1      = (float*)take((size_t)N * 4 * sizeof(float));
  float* ad1      = (float*)take((size_t)N * 4 * sizeof(float));
  float* as2      = (float*)take((size_t)N * sizeof(float));
  float* ad2      = (float*)take((size_t)N * sizeof(float));
  int*   cnt      = (int*)take((size_t)N * sizeof(int));
  int*   row_start= (int*)take((size_t)(N + 1) * sizeof(int));
  int*   cursor   = (int*)take((size_t)N * sizeof(int));
  int*   csr_src  = (int*)take((size_t)E * sizeof(int));
  float* pooled   = (float*)take((size_t)GROUPS * 64 * sizeof(float));
  float* cntf     = (float*)take((size_t)GROUPS * sizeof(float));
  float* w1       = (float*)take((size_t)E * 4 * sizeof(float));
  float* wself1   = (float*)take((size_t)N * 4 * sizeof(float));
  float* winv1    = (float*)take((size_t)N * 4 * sizeof(float));
  float* h2       = (float*)take((size_t)N * 64 * sizeof(float));
  // conv2 edge buffers alias conv1's (dead after gather1w)
  float* w2     = w1;
  float* wself2 = wself1;
  float* winv2  = winv1;

  hipMemsetAsync(cnt, 0, (size_t)N * sizeof(int), stream);
  hipMemsetAsync(pooled, 0, (size_t)GROUPS * 64 * sizeof(float), stream);
  hipMemsetAsync(cntf, 0, (size_t)GROUPS * sizeof(float), stream);

  // conv1 linear + fused attention coefficients
  gemm1_kernel<<<(N + 31) / 32, 256, 0, stream>>>(x, W1, atts1, attd1, h1b, as1, ad1, N);

  // CSR by dst
  hist_kernel<<<(E + 255) / 256, 256, 0, stream>>>(dst, cnt, E);
  scan_kernel<<<1, 1024, 0, stream>>>(cnt, row_start, cursor, N);
  scatter_kernel<<<(E + 255) / 256, 256, 0, stream>>>(src, dst, cursor, csr_src, E);

  // conv1: edge weights then pure gather
  edge_w1_kernel<<<(N + 3) / 4, 256, 0, stream>>>(as1, ad1, row_start, csr_src, w1, wself1, winv1, N);
  gather1w_kernel<<<(N + 3) / 4, 256, 0, stream>>>(h1b, w1, wself1, winv1, b1, row_start, csr_src, hmidb, N);

  // conv2
  gemm2_kernel<<<(N + 31) / 32, 256, 0, stream>>>(hmidb, W2, atts2, attd2, h2b, as2, ad2, N);
  edge_w2_kernel<<<(N + 3) / 4, 256, 0, stream>>>(as2, ad2, row_start, csr_src, w2, wself2, winv2, N);
  gather2w_kernel<<<(N + 3) / 4, 256, 0, stream>>>(h2b, w2, wself2, winv2, b2, row_start, csr_src, h2, N);

  // pooling + classifier
  pool_kernel<<<((N + 63) / 64 + 3) / 4, 256, 0, stream>>>(h2, batch, pooled, cntf, N);
  final_kernel<<<1, 64, 0, stream>>>(pooled, cntf, Wc, bc, out);

  (void)n_in; (void)out_size; (void)ws_size;
}

// Round 4
// 428.194 us; speedup vs baseline: 1.6271x; 1.2373x over previous
//
#include <hip/hip_runtime.h>
#include <hip/hip_bf16.h>

constexpr int HEADS  = 4;
constexpr int HID    = 64;
constexpr int IN_F   = 128;
constexpr int GROUPS = 64;
constexpr float NEG_SLOPE = 0.2f;
constexpr float EPS_SM    = 1e-16f;

static __device__ __forceinline__ float lrelu(float x) { return x >= 0.f ? x : NEG_SLOPE * x; }
static __device__ __forceinline__ float elu1(float x)  { return x > 0.f ? x : expm1f(x); }

static __device__ __forceinline__ float bf2f(unsigned int u) {
  union { unsigned int i; float f; } x; x.i = u << 16; return x.f;
}
static __device__ __forceinline__ unsigned short f2bf(float f) {
  union { float f; unsigned int i; } x; x.f = f;
  unsigned int lsb = (x.i >> 16) & 1u;
  x.i += 0x7fffu + lsb;
  return (unsigned short)(x.i >> 16);
}

// ---- GEMM1 + fused alpha1: h1b[N,256](bf16) = x @ W1 ; as1/ad1[N,4] ----
__global__ __launch_bounds__(256) void gemm1_kernel(
    const float* __restrict__ x, const float* __restrict__ W1,
    const float* __restrict__ att_s, const float* __restrict__ att_d,
    unsigned short* __restrict__ h1b, float* __restrict__ as1, float* __restrict__ ad1, int N) {
  __shared__ float xs[32][IN_F];
  const int t = threadIdx.x;
  const int row0 = blockIdx.x * 32;
  const int rows = min(32, N - row0);
  {
    const float4* xg = reinterpret_cast<const float4*>(x + (size_t)row0 * IN_F);
    float4* sf = reinterpret_cast<float4*>(&xs[0][0]);
    const int maxf4 = rows * (IN_F / 4);
    for (int i = t; i < 32 * (IN_F / 4); i += 256)
      sf[i] = (i < maxf4) ? xg[i] : make_float4(0.f, 0.f, 0.f, 0.f);
  }
  __syncthreads();
  const int ct = t & 63;   // cols ct*4 .. ct*4+3
  const int rt = t >> 6;   // wave id; rows rt*8 .. rt*8+7
  float acc[8][4];
#pragma unroll
  for (int r = 0; r < 8; r++) { acc[r][0]=0.f; acc[r][1]=0.f; acc[r][2]=0.f; acc[r][3]=0.f; }
  for (int k4 = 0; k4 < IN_F / 4; ++k4) {
    float4 xr[8];
#pragma unroll
    for (int r = 0; r < 8; r++)
      xr[r] = *reinterpret_cast<const float4*>(&xs[rt * 8 + r][k4 * 4]);
#pragma unroll
    for (int kk = 0; kk < 4; kk++) {
      const float4 w = *reinterpret_cast<const float4*>(&W1[(size_t)(k4 * 4 + kk) * 256 + ct * 4]);
#pragma unroll
      for (int r = 0; r < 8; r++) {
        const float a = reinterpret_cast<const float*>(&xr[r])[kk];
        acc[r][0] = fmaf(a, w.x, acc[r][0]);
        acc[r][1] = fmaf(a, w.y, acc[r][1]);
        acc[r][2] = fmaf(a, w.z, acc[r][2]);
        acc[r][3] = fmaf(a, w.w, acc[r][3]);
      }
    }
  }
  // fused alpha: per-row dots with att vectors, reduced over each head's 16 lanes
  const float4 avs = *reinterpret_cast<const float4*>(&att_s[ct * 4]);
  const float4 avd = *reinterpret_cast<const float4*>(&att_d[ct * 4]);
  float ps[8], pd[8];
#pragma unroll
  for (int r = 0; r < 8; r++) {
    ps[r] = acc[r][0]*avs.x + acc[r][1]*avs.y + acc[r][2]*avs.z + acc[r][3]*avs.w;
    pd[r] = acc[r][0]*avd.x + acc[r][1]*avd.y + acc[r][2]*avd.z + acc[r][3]*avd.w;
#pragma unroll
    for (int o = 8; o > 0; o >>= 1) {
      ps[r] += __shfl_xor(ps[r], o, 64);
      pd[r] += __shfl_xor(pd[r], o, 64);
    }
  }
  if ((ct & 15) == 0) {
    const int h = ct >> 4;
#pragma unroll
    for (int r = 0; r < 8; r++) {
      const int row = row0 + rt * 8 + r;
      if (row < N) { as1[(size_t)row * 4 + h] = ps[r]; ad1[(size_t)row * 4 + h] = pd[r]; }
    }
  }
  // bf16 store
#pragma unroll
  for (int r = 0; r < 8; r++) {
    const int row = row0 + rt * 8 + r;
    if (row < N) {
      ushort4 ov;
      ov.x = f2bf(acc[r][0]); ov.y = f2bf(acc[r][1]);
      ov.z = f2bf(acc[r][2]); ov.w = f2bf(acc[r][3]);
      reinterpret_cast<ushort4*>(h1b + (size_t)row * 256)[ct] = ov;
    }
  }
}

// ---------------- CSR build ----------------
__global__ __launch_bounds__(256) void hist_kernel(const int* __restrict__ dst, int* __restrict__ cnt, int E) {
  const int e = blockIdx.x * 256 + threadIdx.x;
  if (e < E) atomicAdd(&cnt[dst[e]], 1);
}

// multi-block scan phase 1: per-block sums of cnt
__global__ __launch_bounds__(256) void block_reduce_kernel(
    const int* __restrict__ cnt, int* __restrict__ bsum, int N) {
  const int i = blockIdx.x * 256 + threadIdx.x;
  int v = (i < N) ? cnt[i] : 0;
#pragma unroll
  for (int o = 32; o > 0; o >>= 1) v += __shfl_xor(v, o, 64);
  __shared__ int ws_[4];
  if ((threadIdx.x & 63) == 0) ws_[threadIdx.x >> 6] = v;
  __syncthreads();
  if (threadIdx.x == 0)
    bsum[blockIdx.x] = ws_[0] + ws_[1] + ws_[2] + ws_[3];
}

// multi-block scan phase 2: exclusive scan of block sums (single block)
__global__ __launch_bounds__(256) void bsum_scan_kernel(
    int* __restrict__ bsum, int* __restrict__ boff, int NB) {
  __shared__ int sdata[256];
  const int t = threadIdx.x;
  int v = (t < NB) ? bsum[t] : 0;
  sdata[t] = v;
  __syncthreads();
  for (int o = 1; o < 256; o <<= 1) {
    int x = (t >= o) ? sdata[t - o] : 0;
    __syncthreads();
    sdata[t] += x;
    __syncthreads();
  }
  if (t < NB) boff[t] = sdata[t] - v;   // exclusive
}

// multi-block scan phase 3: in-block exclusive scan + offset; write row_start & cursor
__global__ __launch_bounds__(256) void block_scan_kernel(
    const int* __restrict__ cnt, const int* __restrict__ boff,
    int* __restrict__ row_start, int* __restrict__ cursor, int N) {
  __shared__ int sdata[256];
  const int t = threadIdx.x;
  const int i = blockIdx.x * 256 + t;
  int v = (i < N) ? cnt[i] : 0;
  sdata[t] = v;
  __syncthreads();
  for (int o = 1; o < 256; o <<= 1) {
    int x = (t >= o) ? sdata[t - o] : 0;
    __syncthreads();
    sdata[t] += x;
    __syncthreads();
  }
  if (i < N) {
    const int rs = boff[blockIdx.x] + sdata[t] - v;
    row_start[i] = rs;
    cursor[i] = rs;
    if (i == N - 1) row_start[N] = rs + v;
  }
}

__global__ __launch_bounds__(256) void scatter_kernel(
    const int* __restrict__ src, const int* __restrict__ dst,
    int* __restrict__ cursor, int* __restrict__ csr_src, int E) {
  const int e = blockIdx.x * 256 + threadIdx.x;
  if (e < E) {
    const int d = dst[e];
    const int pos = atomicAdd(&cursor[d], 1);
    csr_src[pos] = src[e];
  }
}

// ---------------- edge weights conv1 ----------------
__global__ __launch_bounds__(256) void edge_w1_kernel(
    const float* __restrict__ as1, const float* __restrict__ ad1,
    const int* __restrict__ row_start, const int* __restrict__ csr_src,
    float* __restrict__ w1, float* __restrict__ wself, float* __restrict__ winv, int N) {
  const int lane = threadIdx.x & 63;
  const int v = blockIdx.x * 4 + (threadIdx.x >> 6);
  if (v >= N) return;
  const int rs = row_start[v], re = row_start[v + 1];
  const float4 adv = *reinterpret_cast<const float4*>(&ad1[(size_t)v * 4]);
  const float4 asv = *reinterpret_cast<const float4*>(&as1[(size_t)v * 4]);
  const float* adp = reinterpret_cast<const float*>(&adv);
  const float* asp = reinterpret_cast<const float*>(&asv);
  float eself[HEADS], m[HEADS];
#pragma unroll
  for (int h = 0; h < HEADS; h++) { eself[h] = lrelu(asp[h] + adp[h]); m[h] = eself[h]; }
  for (int k = rs + lane; k < re; k += 64) {
    const int s = csr_src[k];
    const float4 av = *reinterpret_cast<const float4*>(&as1[(size_t)s * 4]);
    const float* ap = reinterpret_cast<const float*>(&av);
#pragma unroll
    for (int h = 0; h < HEADS; h++) m[h] = fmaxf(m[h], lrelu(ap[h] + adp[h]));
  }
#pragma unroll
  for (int h = 0; h < HEADS; h++)
#pragma unroll
    for (int o = 32; o > 0; o >>= 1) m[h] = fmaxf(m[h], __shfl_xor(m[h], o, 64));
  float den[HEADS] = {0.f, 0.f, 0.f, 0.f};
  for (int k = rs + lane; k < re; k += 64) {
    const int s = csr_src[k];
    const float4 av = *reinterpret_cast<const float4*>(&as1[(size_t)s * 4]);
    const float* ap = reinterpret_cast<const float*>(&av);
    float4 wv;
    float* wp = reinterpret_cast<float*>(&wv);
#pragma unroll
    for (int h = 0; h < HEADS; h++) {
      const float w = __expf(lrelu(ap[h] + adp[h]) - m[h]);
      wp[h] = w;
      den[h] += w;
    }
    *reinterpret_cast<float4*>(&w1[(size_t)k * 4]) = wv;
  }
#pragma unroll
  for (int h = 0; h < HEADS; h++)
#pragma unroll
    for (int o = 32; o > 0; o >>= 1) den[h] += __shfl_xor(den[h], o, 64);
  if (lane == 0) {
    float4 wsv, wiv;
    float* wsp = reinterpret_cast<float*>(&wsv);
    float* wip = reinterpret_cast<float*>(&wiv);
#pragma unroll
    for (int h = 0; h < HEADS; h++) {
      const float ws_ = __expf(eself[h] - m[h]);
      wsp[h] = ws_;
      wip[h] = 1.f / (den[h] + ws_ + EPS_SM);
    }
    *reinterpret_cast<float4*>(&wself[(size_t)v * 4]) = wsv;
    *reinterpret_cast<float4*>(&winv[(size_t)v * 4]) = wiv;
  }
}

// ---------------- edge weights conv2 (1 head) ----------------
__global__ __launch_bounds__(256) void edge_w2_kernel(
    const float* __restrict__ as2, const float* __restrict__ ad2,
    const int* __restrict__ row_start, const int* __restrict__ csr_src,
    float* __restrict__ w2, float* __restrict__ wself2, float* __restrict__ winv2, int N) {
  const int lane = threadIdx.x & 63;
  const int v = blockIdx.x * 4 + (threadIdx.x >> 6);
  if (v >= N) return;
  const int rs = row_start[v], re = row_start[v + 1];
  const float adv = ad2[v];
  const float eself = lrelu(as2[v] + adv);
  float m = eself;
  for (int k = rs + lane; k < re; k += 64)
    m = fmaxf(m, lrelu(as2[csr_src[k]] + adv));
#pragma unroll
  for (int o = 32; o > 0; o >>= 1) m = fmaxf(m, __shfl_xor(m, o, 64));
  float den = 0.f;
  for (int k = rs + lane; k < re; k += 64) {
    const float w = __expf(lrelu(as2[csr_src[k]] + adv) - m);
    w2[k] = w;
    den += w;
  }
#pragma unroll
  for (int o = 32; o > 0; o >>= 1) den += __shfl_xor(den, o, 64);
  if (lane == 0) {
    const float ws_ = __expf(eself - m);
    wself2[v] = ws_;
    winv2[v] = 1.f / (den + ws_ + EPS_SM);
  }
}

// ---- gather1: bf16 gather, ushort4/lane covers all 4 heads in one transaction ----
__global__ __launch_bounds__(256) void gather1w_kernel(
    const unsigned short* __restrict__ h1b, const float* __restrict__ w1,
    const float* __restrict__ wself, const float* __restrict__ winv,
    const float* __restrict__ b1, const int* __restrict__ row_start,
    const int* __restrict__ csr_src, unsigned short* __restrict__ hmidb, int N) {
  const int lane = threadIdx.x & 63;
  const int v = blockIdx.x * 4 + (threadIdx.x >> 6);
  if (v >= N) return;
  const int hd = lane >> 4;       // head of this lane's 4 channels
  const int rs = row_start[v], re = row_start[v + 1];
  const float ws = wself[(size_t)v * 4 + hd];
  const ushort4 sv = reinterpret_cast<const ushort4*>(h1b + (size_t)v * 256)[lane];
  float4 acc;
  acc.x = ws * bf2f(sv.x); acc.y = ws * bf2f(sv.y);
  acc.z = ws * bf2f(sv.z); acc.w = ws * bf2f(sv.w);
  if (rs < re) {
    int sN = csr_src[rs];
    float wN = w1[(size_t)rs * 4 + hd];
    for (int k = rs; k < re; ++k) {
      const int s = sN;
      const float w = wN;
      const int kn = (k + 1 < re) ? k + 1 : k;
      sN = csr_src[kn];
      wN = w1[(size_t)kn * 4 + hd];
      const ushort4 f = reinterpret_cast<const ushort4*>(h1b + (size_t)s * 256)[lane];
      acc.x = fmaf(w, bf2f(f.x), acc.x);
      acc.y = fmaf(w, bf2f(f.y), acc.y);
      acc.z = fmaf(w, bf2f(f.z), acc.z);
      acc.w = fmaf(w, bf2f(f.w), acc.w);
    }
  }
  const float wi = winv[(size_t)v * 4 + hd];
  const int c0 = lane * 4;
  const float4 bv = *reinterpret_cast<const float4*>(&b1[c0]);
  ushort4 ov;
  ov.x = f2bf(elu1(acc.x * wi + bv.x));
  ov.y = f2bf(elu1(acc.y * wi + bv.y));
  ov.z = f2bf(elu1(acc.z * wi + bv.z));
  ov.w = f2bf(elu1(acc.w * wi + bv.w));
  reinterpret_cast<ushort4*>(hmidb + (size_t)v * 256)[lane] = ov;
}

// ---- GEMM2 + fused alpha2: h2b[N,64](bf16) = hmidb @ W2 ; as2/ad2[N] ----
__global__ __launch_bounds__(256) void gemm2_kernel(
    const unsigned short* __restrict__ A, const float* __restrict__ W,
    const float* __restrict__ att_s, const float* __restrict__ att_d,
    unsigned short* __restrict__ h2b, float* __restrict__ as2, float* __restrict__ ad2, int N) {
  __shared__ float as_[32][256];
  const int t = threadIdx.x;
  const int row0 = blockIdx.x * 32;
  const int rows = min(32, N - row0);
  {
    const uint4* ag = reinterpret_cast<const uint4*>(A + (size_t)row0 * 256);
    const int maxu4 = rows * 32;
    for (int i = t; i < 32 * 32; i += 256) {
      uint4 u = (i < maxu4) ? ag[i] : make_uint4(0u, 0u, 0u, 0u);
      float* dp = &as_[i >> 5][(i & 31) * 8];
      dp[0] = bf2f(u.x & 0xffffu); dp[1] = bf2f(u.x >> 16);
      dp[2] = bf2f(u.y & 0xffffu); dp[3] = bf2f(u.y >> 16);
      dp[4] = bf2f(u.z & 0xffffu); dp[5] = bf2f(u.z >> 16);
      dp[6] = bf2f(u.w & 0xffffu); dp[7] = bf2f(u.w >> 16);
    }
  }
  __syncthreads();
  const int ct = t & 15;  // cols ct*4..+3
  const int rt = t >> 4;  // rows rt*2..+1
  float acc[2][4] = {{0.f,0.f,0.f,0.f},{0.f,0.f,0.f,0.f}};
  for (int k4 = 0; k4 < 64; ++k4) {
    const float4 xr0 = *reinterpret_cast<const float4*>(&as_[rt * 2][k4 * 4]);
    const float4 xr1 = *reinterpret_cast<const float4*>(&as_[rt * 2 + 1][k4 * 4]);
#pragma unroll
    for (int kk = 0; kk < 4; kk++) {
      const float4 w = *reinterpret_cast<const float4*>(&W[(size_t)(k4 * 4 + kk) * 64 + ct * 4]);
      const float a0 = reinterpret_cast<const float*>(&xr0)[kk];
      const float a1 = reinterpret_cast<const float*>(&xr1)[kk];
      acc[0][0] = fmaf(a0, w.x, acc[0][0]); acc[0][1] = fmaf(a0, w.y, acc[0][1]);
      acc[0][2] = fmaf(a0, w.z, acc[0][2]); acc[0][3] = fmaf(a0, w.w, acc[0][3]);
      acc[1][0] = fmaf(a1, w.x, acc[1][0]); acc[1][1] = fmaf(a1, w.y, acc[1][1]);
      acc[1][2] = fmaf(a1, w.z, acc[1][2]); acc[1][3] = fmaf(a1, w.w, acc[1][3]);
    }
  }
  // fused alpha2: dot over 64 cols, reduce across the 16 ct lanes
  const float4 avs = *reinterpret_cast<const float4*>(&att_s[ct * 4]);
  const float4 avd = *reinterpret_cast<const float4*>(&att_d[ct * 4]);
  float ps[2], pd[2];
#pragma unroll
  for (int r = 0; r < 2; r++) {
    ps[r] = acc[r][0]*avs.x + acc[r][1]*avs.y + acc[r][2]*avs.z + acc[r][3]*avs.w;
    pd[r] = acc[r][0]*avd.x + acc[r][1]*avd.y + acc[r][2]*avd.z + acc[r][3]*avd.w;
#pragma unroll
    for (int o = 8; o > 0; o >>= 1) {
      ps[r] += __shfl_xor(ps[r], o, 64);
      pd[r] += __shfl_xor(pd[r], o, 64);
    }
  }
  if (((t & 63) & 15) == 0) {
#pragma unroll
    for (int r = 0; r < 2; r++) {
      const int row = row0 + rt * 2 + r;
      if (row < N) { as2[row] = ps[r]; ad2[row] = pd[r]; }
    }
  }
#pragma unroll
  for (int r = 0; r < 2; r++) {
    const int row = row0 + rt * 2 + r;
    if (row < N) {
      ushort4 ov;
      ov.x = f2bf(acc[r][0]); ov.y = f2bf(acc[r][1]);
      ov.z = f2bf(acc[r][2]); ov.w = f2bf(acc[r][3]);
      reinterpret_cast<ushort4*>(h2b + (size_t)row * 64)[ct] = ov;
    }
  }
}

// ---- gather2: bf16, 2 edges per wave iteration ----
__global__ __launch_bounds__(256) void gather2w_kernel(
    const unsigned short* __restrict__ h2b, const float* __restrict__ w2,
    const float* __restrict__ wself2, const float* __restrict__ winv2,
    const float* __restrict__ b2, const int* __restrict__ row_start,
    const int* __restrict__ csr_src, float* __restrict__ h2, int N) {
  const int lane = threadIdx.x & 63;
  const int v = blockIdx.x * 4 + (threadIdx.x >> 6);
  if (v >= N) return;
  const int half = lane >> 5;   // 0/1: which edge of the pair
  const int cl = lane & 31;     // channels 2cl, 2cl+1
  const int rs = row_start[v], re = row_start[v + 1];
  float ax = 0.f, ay = 0.f;
  if (half == 0) {
    const unsigned int u = reinterpret_cast<const unsigned int*>(h2b + (size_t)v * 64)[cl];
    const float ws = wself2[v];
    ax = ws * bf2f(u & 0xffffu);
    ay = ws * bf2f(u >> 16);
  }
  for (int k = rs + half; k < re; k += 2) {
    const int s = csr_src[k];
    const float w = w2[k];
    const unsigned int u = reinterpret_cast<const unsigned int*>(h2b + (size_t)s * 64)[cl];
    ax = fmaf(w, bf2f(u & 0xffffu), ax);
    ay = fmaf(w, bf2f(u >> 16), ay);
  }
  ax += __shfl_xor(ax, 32, 64);
  ay += __shfl_xor(ay, 32, 64);
  if (half == 0) {
    const float wi = winv2[v];
    float2 o;
    o.x = elu1(ax * wi + b2[2 * cl]);
    o.y = elu1(ay * wi + b2[2 * cl + 1]);
    reinterpret_cast<float2*>(h2 + (size_t)v * 64)[cl] = o;
  }
}

// ---------------- mean-pool over sorted batch ----------------
__global__ __launch_bounds__(256) void pool_kernel(
    const float* __restrict__ h2, const int* __restrict__ batch,
    float* __restrict__ pooled, float* __restrict__ cntf, int N) {
  const int lane = threadIdx.x & 63;
  const int gw = blockIdx.x * 4 + (threadIdx.x >> 6);
  const int s = gw * 64;
  if (s >= N) return;
  const int e = min(s + 64, N);
  int cur = batch[s];
  float racc = 0.f;
  int rc = 0;
  for (int v = s; v < e; v++) {
    const int g = batch[v];
    if (g != cur) {
      atomicAdd(&pooled[(size_t)cur * 64 + lane], racc);
      if (lane == 0) atomicAdd(&cntf[cur], (float)rc);
      racc = 0.f; rc = 0; cur = g;
    }
    racc += h2[(size_t)v * 64 + lane];
    rc++;
  }
  atomicAdd(&pooled[(size_t)cur * 64 + lane], racc);
  if (lane == 0) atomicAdd(&cntf[cur], (float)rc);
}

// ---------------- classifier ----------------
__global__ __launch_bounds__(64) void final_kernel(
    const float* __restrict__ pooled, const float* __restrict__ cntf,
    const float* __restrict__ Wc, const float* __restrict__ bc, float* __restrict__ out) {
  const int g = threadIdx.x;
  float acc = 0.f;
  for (int c = 0; c < 64; c++) acc = fmaf(pooled[(size_t)g * 64 + c], Wc[c], acc);
  const float cnt = fmaxf(cntf[g], 1.0f);
  out[g] = acc / cnt + bc[0];
}

extern "C" void kernel_launch(void* const* d_in, const int* in_sizes, int n_in,
                              void* d_out, int out_size, void* d_ws, size_t ws_size,
                              hipStream_t stream) {
  const float* x     = (const float*)d_in[0];
  const int*   ei    = (const int*)d_in[1];
  const int*   batch = (const int*)d_in[2];
  const float* W1    = (const float*)d_in[3];
  const float* atts1 = (const float*)d_in[4];
  const float* attd1 = (const float*)d_in[5];
  const float* b1    = (const float*)d_in[6];
  const float* W2    = (const float*)d_in[7];
  const float* atts2 = (const float*)d_in[8];
  const float* attd2 = (const float*)d_in[9];
  const float* b2    = (const float*)d_in[10];
  const float* Wc    = (const float*)d_in[11];
  const float* bc    = (const float*)d_in[12];
  float* out = (float*)d_out;

  const int N = in_sizes[0] / IN_F;   // 50000
  const int E = in_sizes[1] / 2;      // 800000
  const int* src = ei;
  const int* dst = ei + E;
  const int NB = (N + 255) / 256;     // scan blocks

  char* ws = (char*)d_ws;
  size_t off = 0;
  auto take = [&](size_t bytes) -> void* {
    void* p = ws + off;
    off = (off + bytes + 255) & ~(size_t)255;
    return p;
  };
  unsigned short* h1b   = (unsigned short*)take((size_t)N * 256 * 2);
  unsigned short* hmidb = (unsigned short*)take((size_t)N * 256 * 2);
  unsigned short* h2b   = (unsigned short*)take((size_t)N * 64 * 2);
  float* as1      = (float*)take((size_t)N * 4 * sizeof(float));
  float* ad1      = (float*)take((size_t)N * 4 * sizeof(float));
  float* as2      = (float*)take((size_t)N * sizeof(float));
  float* ad2      = (float*)take((size_t)N * sizeof(float));
  int*   cnt      = (int*)take((size_t)N * sizeof(int));
  int*   row_start= (int*)take((size_t)(N + 1) * sizeof(int));
  int*   cursor   = (int*)take((size_t)N * sizeof(int));
  int*   csr_src  = (int*)take((size_t)E * sizeof(int));
  int*   bsum     = (int*)take((size_t)NB * sizeof(int));
  int*   boff     = (int*)take((size_t)NB * sizeof(int));
  float* pooled   = (float*)take((size_t)GROUPS * 64 * sizeof(float));
  float* cntf     = (float*)take((size_t)GROUPS * sizeof(float));
  float* w1       = (float*)take((size_t)E * 4 * sizeof(float));
  float* wself1   = (float*)take((size_t)N * 4 * sizeof(float));
  float* winv1    = (float*)take((size_t)N * 4 * sizeof(float));
  float* h2       = (float*)take((size_t)N * 64 * sizeof(float));
  // conv2 edge buffers alias conv1's (dead after gather1w)
  float* w2     = w1;
  float* wself2 = wself1;
  float* winv2  = winv1;

  hipMemsetAsync(cnt, 0, (size_t)N * sizeof(int), stream);
  hipMemsetAsync(pooled, 0, (size_t)GROUPS * 64 * sizeof(float), stream);
  hipMemsetAsync(cntf, 0, (size_t)GROUPS * sizeof(float), stream);

  // conv1 linear + fused attention coefficients
  gemm1_kernel<<<(N + 31) / 32, 256, 0, stream>>>(x, W1, atts1, attd1, h1b, as1, ad1, N);

  // CSR by dst (multi-block scan)
  hist_kernel<<<(E + 255) / 256, 256, 0, stream>>>(dst, cnt, E);
  block_reduce_kernel<<<NB, 256, 0, stream>>>(cnt, bsum, N);
  bsum_scan_kernel<<<1, 256, 0, stream>>>(bsum, boff, NB);
  block_scan_kernel<<<NB, 256, 0, stream>>>(cnt, boff, row_start, cursor, N);
  scatter_kernel<<<(E + 255) / 256, 256, 0, stream>>>(src, dst, cursor, csr_src, E);

  // conv1: edge weights then pure gather
  edge_w1_kernel<<<(N + 3) / 4, 256, 0, stream>>>(as1, ad1, row_start, csr_src, w1, wself1, winv1, N);
  gather1w_kernel<<<(N + 3) / 4, 256, 0, stream>>>(h1b, w1, wself1, winv1, b1, row_start, csr_src, hmidb, N);

  // conv2
  gemm2_kernel<<<(N + 31) / 32, 256, 0, stream>>>(hmidb, W2, atts2, attd2, h2b, as2, ad2, N);
  edge_w2_kernel<<<(N + 3) / 4, 256, 0, stream>>>(as2, ad2, row_start, csr_src, w2, wself2, winv2, N);
  gather2w_kernel<<<(N + 3) / 4, 256, 0, stream>>>(h2b, w2, wself2, winv2, b2, row_start, csr_src, h2, N);

  // pooling + classifier
  pool_kernel<<<((N + 63) / 64 + 3) / 4, 256, 0, stream>>>(h2, batch, pooled, cntf, N);
  final_kernel<<<1, 64, 0, stream>>>(pooled, cntf, Wc, bc, out);

  (void)n_in; (void)out_size; (void)ws_size;
}

// Round 5
// 375.699 us; speedup vs baseline: 1.8545x; 1.1397x over previous
//
#include <hip/hip_runtime.h>
#include <hip/hip_bf16.h>

constexpr int HEADS  = 4;
constexpr int HID    = 64;
constexpr int IN_F   = 128;
constexpr int GROUPS = 64;
constexpr float NEG_SLOPE = 0.2f;
constexpr float EPS_SM    = 1e-16f;

static __device__ __forceinline__ float lrelu(float x) { return x >= 0.f ? x : NEG_SLOPE * x; }
static __device__ __forceinline__ float elu1(float x)  { return x > 0.f ? x : expm1f(x); }

static __device__ __forceinline__ float bf2f(unsigned int u) {
  union { unsigned int i; float f; } x; x.i = u << 16; return x.f;
}
static __device__ __forceinline__ unsigned short f2bf(float f) {
  union { float f; unsigned int i; } x; x.f = f;
  unsigned int lsb = (x.i >> 16) & 1u;
  x.i += 0x7fffu + lsb;
  return (unsigned short)(x.i >> 16);
}

// ---- GEMM1 + fused alpha1: h1b[N,256](bf16) = x @ W1 ; as1/ad1[N,4] ----
__global__ __launch_bounds__(256) void gemm1_kernel(
    const float* __restrict__ x, const float* __restrict__ W1,
    const float* __restrict__ att_s, const float* __restrict__ att_d,
    unsigned short* __restrict__ h1b, float* __restrict__ as1, float* __restrict__ ad1, int N) {
  __shared__ float xs[32][IN_F];
  const int t = threadIdx.x;
  const int row0 = blockIdx.x * 32;
  const int rows = min(32, N - row0);
  {
    const float4* xg = reinterpret_cast<const float4*>(x + (size_t)row0 * IN_F);
    float4* sf = reinterpret_cast<float4*>(&xs[0][0]);
    const int maxf4 = rows * (IN_F / 4);
    for (int i = t; i < 32 * (IN_F / 4); i += 256)
      sf[i] = (i < maxf4) ? xg[i] : make_float4(0.f, 0.f, 0.f, 0.f);
  }
  __syncthreads();
  const int ct = t & 63;   // cols ct*4 .. ct*4+3
  const int rt = t >> 6;   // wave id; rows rt*8 .. rt*8+7
  float acc[8][4];
#pragma unroll
  for (int r = 0; r < 8; r++) { acc[r][0]=0.f; acc[r][1]=0.f; acc[r][2]=0.f; acc[r][3]=0.f; }
  for (int k4 = 0; k4 < IN_F / 4; ++k4) {
    float4 xr[8];
#pragma unroll
    for (int r = 0; r < 8; r++)
      xr[r] = *reinterpret_cast<const float4*>(&xs[rt * 8 + r][k4 * 4]);
#pragma unroll
    for (int kk = 0; kk < 4; kk++) {
      const float4 w = *reinterpret_cast<const float4*>(&W1[(size_t)(k4 * 4 + kk) * 256 + ct * 4]);
#pragma unroll
      for (int r = 0; r < 8; r++) {
        const float a = reinterpret_cast<const float*>(&xr[r])[kk];
        acc[r][0] = fmaf(a, w.x, acc[r][0]);
        acc[r][1] = fmaf(a, w.y, acc[r][1]);
        acc[r][2] = fmaf(a, w.z, acc[r][2]);
        acc[r][3] = fmaf(a, w.w, acc[r][3]);
      }
    }
  }
  // fused alpha: per-row dots with att vectors, reduced over each head's 16 lanes
  const float4 avs = *reinterpret_cast<const float4*>(&att_s[ct * 4]);
  const float4 avd = *reinterpret_cast<const float4*>(&att_d[ct * 4]);
  float ps[8], pd[8];
#pragma unroll
  for (int r = 0; r < 8; r++) {
    ps[r] = acc[r][0]*avs.x + acc[r][1]*avs.y + acc[r][2]*avs.z + acc[r][3]*avs.w;
    pd[r] = acc[r][0]*avd.x + acc[r][1]*avd.y + acc[r][2]*avd.z + acc[r][3]*avd.w;
#pragma unroll
    for (int o = 8; o > 0; o >>= 1) {
      ps[r] += __shfl_xor(ps[r], o, 64);
      pd[r] += __shfl_xor(pd[r], o, 64);
    }
  }
  if ((ct & 15) == 0) {
    const int h = ct >> 4;
#pragma unroll
    for (int r = 0; r < 8; r++) {
      const int row = row0 + rt * 8 + r;
      if (row < N) { as1[(size_t)row * 4 + h] = ps[r]; ad1[(size_t)row * 4 + h] = pd[r]; }
    }
  }
  // bf16 store
#pragma unroll
  for (int r = 0; r < 8; r++) {
    const int row = row0 + rt * 8 + r;
    if (row < N) {
      ushort4 ov;
      ov.x = f2bf(acc[r][0]); ov.y = f2bf(acc[r][1]);
      ov.z = f2bf(acc[r][2]); ov.w = f2bf(acc[r][3]);
      reinterpret_cast<ushort4*>(h1b + (size_t)row * 256)[ct] = ov;
    }
  }
}

// ---------------- CSR build ----------------
__global__ __launch_bounds__(256) void hist_kernel(const int* __restrict__ dst, int* __restrict__ cnt, int E) {
  const int e = blockIdx.x * 256 + threadIdx.x;
  if (e < E) atomicAdd(&cnt[dst[e]], 1);
}

// multi-block scan phase 1: per-block sums of cnt
__global__ __launch_bounds__(256) void block_reduce_kernel(
    const int* __restrict__ cnt, int* __restrict__ bsum, int N) {
  const int i = blockIdx.x * 256 + threadIdx.x;
  int v = (i < N) ? cnt[i] : 0;
#pragma unroll
  for (int o = 32; o > 0; o >>= 1) v += __shfl_xor(v, o, 64);
  __shared__ int ws_[4];
  if ((threadIdx.x & 63) == 0) ws_[threadIdx.x >> 6] = v;
  __syncthreads();
  if (threadIdx.x == 0)
    bsum[blockIdx.x] = ws_[0] + ws_[1] + ws_[2] + ws_[3];
}

// multi-block scan phase 2: exclusive scan of block sums (single block)
__global__ __launch_bounds__(256) void bsum_scan_kernel(
    int* __restrict__ bsum, int* __restrict__ boff, int NB) {
  __shared__ int sdata[256];
  const int t = threadIdx.x;
  int v = (t < NB) ? bsum[t] : 0;
  sdata[t] = v;
  __syncthreads();
  for (int o = 1; o < 256; o <<= 1) {
    int x = (t >= o) ? sdata[t - o] : 0;
    __syncthreads();
    sdata[t] += x;
    __syncthreads();
  }
  if (t < NB) boff[t] = sdata[t] - v;   // exclusive
}

// multi-block scan phase 3: in-block exclusive scan + offset; write row_start & cursor
__global__ __launch_bounds__(256) void block_scan_kernel(
    const int* __restrict__ cnt, const int* __restrict__ boff,
    int* __restrict__ row_start, int* __restrict__ cursor, int N) {
  __shared__ int sdata[256];
  const int t = threadIdx.x;
  const int i = blockIdx.x * 256 + t;
  int v = (i < N) ? cnt[i] : 0;
  sdata[t] = v;
  __syncthreads();
  for (int o = 1; o < 256; o <<= 1) {
    int x = (t >= o) ? sdata[t - o] : 0;
    __syncthreads();
    sdata[t] += x;
    __syncthreads();
  }
  if (i < N) {
    const int rs = boff[blockIdx.x] + sdata[t] - v;
    row_start[i] = rs;
    cursor[i] = rs;
    if (i == N - 1) row_start[N] = rs + v;
  }
}

__global__ __launch_bounds__(256) void scatter_kernel(
    const int* __restrict__ src, const int* __restrict__ dst,
    int* __restrict__ cursor, int* __restrict__ csr_src, int E) {
  const int e = blockIdx.x * 256 + threadIdx.x;
  if (e < E) {
    const int d = dst[e];
    const int pos = atomicAdd(&cursor[d], 1);
    csr_src[pos] = src[e];
  }
}

// ---------------- edge weights conv1 ----------------
__global__ __launch_bounds__(256) void edge_w1_kernel(
    const float* __restrict__ as1, const float* __restrict__ ad1,
    const int* __restrict__ row_start, const int* __restrict__ csr_src,
    float* __restrict__ w1, float* __restrict__ wself, float* __restrict__ winv, int N) {
  const int lane = threadIdx.x & 63;
  const int v = blockIdx.x * 4 + (threadIdx.x >> 6);
  if (v >= N) return;
  const int rs = row_start[v], re = row_start[v + 1];
  const float4 adv = *reinterpret_cast<const float4*>(&ad1[(size_t)v * 4]);
  const float4 asv = *reinterpret_cast<const float4*>(&as1[(size_t)v * 4]);
  const float* adp = reinterpret_cast<const float*>(&adv);
  const float* asp = reinterpret_cast<const float*>(&asv);
  float eself[HEADS], m[HEADS];
#pragma unroll
  for (int h = 0; h < HEADS; h++) { eself[h] = lrelu(asp[h] + adp[h]); m[h] = eself[h]; }
  for (int k = rs + lane; k < re; k += 64) {
    const int s = csr_src[k];
    const float4 av = *reinterpret_cast<const float4*>(&as1[(size_t)s * 4]);
    const float* ap = reinterpret_cast<const float*>(&av);
#pragma unroll
    for (int h = 0; h < HEADS; h++) m[h] = fmaxf(m[h], lrelu(ap[h] + adp[h]));
  }
#pragma unroll
  for (int h = 0; h < HEADS; h++)
#pragma unroll
    for (int o = 32; o > 0; o >>= 1) m[h] = fmaxf(m[h], __shfl_xor(m[h], o, 64));
  float den[HEADS] = {0.f, 0.f, 0.f, 0.f};
  for (int k = rs + lane; k < re; k += 64) {
    const int s = csr_src[k];
    const float4 av = *reinterpret_cast<const float4*>(&as1[(size_t)s * 4]);
    const float* ap = reinterpret_cast<const float*>(&av);
    float4 wv;
    float* wp = reinterpret_cast<float*>(&wv);
#pragma unroll
    for (int h = 0; h < HEADS; h++) {
      const float w = __expf(lrelu(ap[h] + adp[h]) - m[h]);
      wp[h] = w;
      den[h] += w;
    }
    *reinterpret_cast<float4*>(&w1[(size_t)k * 4]) = wv;
  }
#pragma unroll
  for (int h = 0; h < HEADS; h++)
#pragma unroll
    for (int o = 32; o > 0; o >>= 1) den[h] += __shfl_xor(den[h], o, 64);
  if (lane == 0) {
    float4 wsv, wiv;
    float* wsp = reinterpret_cast<float*>(&wsv);
    float* wip = reinterpret_cast<float*>(&wiv);
#pragma unroll
    for (int h = 0; h < HEADS; h++) {
      const float ws_ = __expf(eself[h] - m[h]);
      wsp[h] = ws_;
      wip[h] = 1.f / (den[h] + ws_ + EPS_SM);
    }
    *reinterpret_cast<float4*>(&wself[(size_t)v * 4]) = wsv;
    *reinterpret_cast<float4*>(&winv[(size_t)v * 4]) = wiv;
  }
}

// ---------------- edge weights conv2 (1 head) ----------------
__global__ __launch_bounds__(256) void edge_w2_kernel(
    const float* __restrict__ as2, const float* __restrict__ ad2,
    const int* __restrict__ row_start, const int* __restrict__ csr_src,
    float* __restrict__ w2, float* __restrict__ wself2, float* __restrict__ winv2, int N) {
  const int lane = threadIdx.x & 63;
  const int v = blockIdx.x * 4 + (threadIdx.x >> 6);
  if (v >= N) return;
  const int rs = row_start[v], re = row_start[v + 1];
  const float adv = ad2[v];
  const float eself = lrelu(as2[v] + adv);
  float m = eself;
  for (int k = rs + lane; k < re; k += 64)
    m = fmaxf(m, lrelu(as2[csr_src[k]] + adv));
#pragma unroll
  for (int o = 32; o > 0; o >>= 1) m = fmaxf(m, __shfl_xor(m, o, 64));
  float den = 0.f;
  for (int k = rs + lane; k < re; k += 64) {
    const float w = __expf(lrelu(as2[csr_src[k]] + adv) - m);
    w2[k] = w;
    den += w;
  }
#pragma unroll
  for (int o = 32; o > 0; o >>= 1) den += __shfl_xor(den, o, 64);
  if (lane == 0) {
    const float ws_ = __expf(eself - m);
    wself2[v] = ws_;
    winv2[v] = 1.f / (den + ws_ + EPS_SM);
  }
}

// ---- gather1: bf16 gather, 4-edge chunks, one-chunk-ahead meta prefetch ----
__global__ __launch_bounds__(256) void gather1w_kernel(
    const unsigned short* __restrict__ h1b, const float* __restrict__ w1,
    const float* __restrict__ wself, const float* __restrict__ winv,
    const float* __restrict__ b1, const int* __restrict__ row_start,
    const int* __restrict__ csr_src, unsigned short* __restrict__ hmidb, int N) {
  const int lane = threadIdx.x & 63;
  const int v = blockIdx.x * 4 + (threadIdx.x >> 6);
  if (v >= N) return;
  const int hd = lane >> 4;       // head of this lane's 4 channels
  const int rs = row_start[v], re = row_start[v + 1];
  const float ws = wself[(size_t)v * 4 + hd];
  const ushort4 sv = reinterpret_cast<const ushort4*>(h1b + (size_t)v * 256)[lane];
  float4 acc;
  acc.x = ws * bf2f(sv.x); acc.y = ws * bf2f(sv.y);
  acc.z = ws * bf2f(sv.z); acc.w = ws * bf2f(sv.w);
  if (rs < re) {
    const int rl = re - 1;
    int k = rs;
    // prime chunk 0 metadata (clamped indices, zero-masked weights)
    int s0 = csr_src[k];
    int s1 = csr_src[min(k + 1, rl)];
    int s2 = csr_src[min(k + 2, rl)];
    int s3 = csr_src[min(k + 3, rl)];
    float y0 = w1[(size_t)k * 4 + hd];
    float t1 = w1[(size_t)min(k + 1, rl) * 4 + hd];
    float t2 = w1[(size_t)min(k + 2, rl) * 4 + hd];
    float t3 = w1[(size_t)min(k + 3, rl) * 4 + hd];
    float y1 = (k + 1 < re) ? t1 : 0.f;
    float y2 = (k + 2 < re) ? t2 : 0.f;
    float y3 = (k + 3 < re) ? t3 : 0.f;
    while (k < re) {
      const int kn = k + 4;
      // issue 4 independent feature loads
      const ushort4 f0 = reinterpret_cast<const ushort4*>(h1b + (size_t)s0 * 256)[lane];
      const ushort4 f1 = reinterpret_cast<const ushort4*>(h1b + (size_t)s1 * 256)[lane];
      const ushort4 f2 = reinterpret_cast<const ushort4*>(h1b + (size_t)s2 * 256)[lane];
      const ushort4 f3 = reinterpret_cast<const ushort4*>(h1b + (size_t)s3 * 256)[lane];
      // prefetch next chunk metadata (clamped; harmless when past end)
      const int kc0 = min(kn, rl), kc1 = min(kn + 1, rl), kc2 = min(kn + 2, rl), kc3 = min(kn + 3, rl);
      const int n0 = csr_src[kc0];
      const int n1 = csr_src[kc1];
      const int n2 = csr_src[kc2];
      const int n3 = csr_src[kc3];
      const float u0 = w1[(size_t)kc0 * 4 + hd];
      const float u1 = w1[(size_t)kc1 * 4 + hd];
      const float u2 = w1[(size_t)kc2 * 4 + hd];
      const float u3 = w1[(size_t)kc3 * 4 + hd];
      // FMA current chunk
      acc.x = fmaf(y0, bf2f(f0.x), acc.x); acc.y = fmaf(y0, bf2f(f0.y), acc.y);
      acc.z = fmaf(y0, bf2f(f0.z), acc.z); acc.w = fmaf(y0, bf2f(f0.w), acc.w);
      acc.x = fmaf(y1, bf2f(f1.x), acc.x); acc.y = fmaf(y1, bf2f(f1.y), acc.y);
      acc.z = fmaf(y1, bf2f(f1.z), acc.z); acc.w = fmaf(y1, bf2f(f1.w), acc.w);
      acc.x = fmaf(y2, bf2f(f2.x), acc.x); acc.y = fmaf(y2, bf2f(f2.y), acc.y);
      acc.z = fmaf(y2, bf2f(f2.z), acc.z); acc.w = fmaf(y2, bf2f(f2.w), acc.w);
      acc.x = fmaf(y3, bf2f(f3.x), acc.x); acc.y = fmaf(y3, bf2f(f3.y), acc.y);
      acc.z = fmaf(y3, bf2f(f3.z), acc.z); acc.w = fmaf(y3, bf2f(f3.w), acc.w);
      // rotate
      s0 = n0; s1 = n1; s2 = n2; s3 = n3;
      y0 = (kn     < re) ? u0 : 0.f;
      y1 = (kn + 1 < re) ? u1 : 0.f;
      y2 = (kn + 2 < re) ? u2 : 0.f;
      y3 = (kn + 3 < re) ? u3 : 0.f;
      k = kn;
    }
  }
  const float wi = winv[(size_t)v * 4 + hd];
  const int c0 = lane * 4;
  const float4 bv = *reinterpret_cast<const float4*>(&b1[c0]);
  ushort4 ov;
  ov.x = f2bf(elu1(acc.x * wi + bv.x));
  ov.y = f2bf(elu1(acc.y * wi + bv.y));
  ov.z = f2bf(elu1(acc.z * wi + bv.z));
  ov.w = f2bf(elu1(acc.w * wi + bv.w));
  reinterpret_cast<ushort4*>(hmidb + (size_t)v * 256)[lane] = ov;
}

// ---- GEMM2 + fused alpha2: h2b[N,64](bf16) = hmidb @ W2 ; as2/ad2[N] ----
__global__ __launch_bounds__(256) void gemm2_kernel(
    const unsigned short* __restrict__ A, const float* __restrict__ W,
    const float* __restrict__ att_s, const float* __restrict__ att_d,
    unsigned short* __restrict__ h2b, float* __restrict__ as2, float* __restrict__ ad2, int N) {
  __shared__ float as_[32][256];
  const int t = threadIdx.x;
  const int row0 = blockIdx.x * 32;
  const int rows = min(32, N - row0);
  {
    const uint4* ag = reinterpret_cast<const uint4*>(A + (size_t)row0 * 256);
    const int maxu4 = rows * 32;
    for (int i = t; i < 32 * 32; i += 256) {
      uint4 u = (i < maxu4) ? ag[i] : make_uint4(0u, 0u, 0u, 0u);
      float* dp = &as_[i >> 5][(i & 31) * 8];
      dp[0] = bf2f(u.x & 0xffffu); dp[1] = bf2f(u.x >> 16);
      dp[2] = bf2f(u.y & 0xffffu); dp[3] = bf2f(u.y >> 16);
      dp[4] = bf2f(u.z & 0xffffu); dp[5] = bf2f(u.z >> 16);
      dp[6] = bf2f(u.w & 0xffffu); dp[7] = bf2f(u.w >> 16);
    }
  }
  __syncthreads();
  const int ct = t & 15;  // cols ct*4..+3
  const int rt = t >> 4;  // rows rt*2..+1
  float acc[2][4] = {{0.f,0.f,0.f,0.f},{0.f,0.f,0.f,0.f}};
  for (int k4 = 0; k4 < 64; ++k4) {
    const float4 xr0 = *reinterpret_cast<const float4*>(&as_[rt * 2][k4 * 4]);
    const float4 xr1 = *reinterpret_cast<const float4*>(&as_[rt * 2 + 1][k4 * 4]);
#pragma unroll
    for (int kk = 0; kk < 4; kk++) {
      const float4 w = *reinterpret_cast<const float4*>(&W[(size_t)(k4 * 4 + kk) * 64 + ct * 4]);
      const float a0 = reinterpret_cast<const float*>(&xr0)[kk];
      const float a1 = reinterpret_cast<const float*>(&xr1)[kk];
      acc[0][0] = fmaf(a0, w.x, acc[0][0]); acc[0][1] = fmaf(a0, w.y, acc[0][1]);
      acc[0][2] = fmaf(a0, w.z, acc[0][2]); acc[0][3] = fmaf(a0, w.w, acc[0][3]);
      acc[1][0] = fmaf(a1, w.x, acc[1][0]); acc[1][1] = fmaf(a1, w.y, acc[1][1]);
      acc[1][2] = fmaf(a1, w.z, acc[1][2]); acc[1][3] = fmaf(a1, w.w, acc[1][3]);
    }
  }
  // fused alpha2: dot over 64 cols, reduce across the 16 ct lanes
  const float4 avs = *reinterpret_cast<const float4*>(&att_s[ct * 4]);
  const float4 avd = *reinterpret_cast<const float4*>(&att_d[ct * 4]);
  float ps[2], pd[2];
#pragma unroll
  for (int r = 0; r < 2; r++) {
    ps[r] = acc[r][0]*avs.x + acc[r][1]*avs.y + acc[r][2]*avs.z + acc[r][3]*avs.w;
    pd[r] = acc[r][0]*avd.x + acc[r][1]*avd.y + acc[r][2]*avd.z + acc[r][3]*avd.w;
#pragma unroll
    for (int o = 8; o > 0; o >>= 1) {
      ps[r] += __shfl_xor(ps[r], o, 64);
      pd[r] += __shfl_xor(pd[r], o, 64);
    }
  }
  if (((t & 63) & 15) == 0) {
#pragma unroll
    for (int r = 0; r < 2; r++) {
      const int row = row0 + rt * 2 + r;
      if (row < N) { as2[row] = ps[r]; ad2[row] = pd[r]; }
    }
  }
#pragma unroll
  for (int r = 0; r < 2; r++) {
    const int row = row0 + rt * 2 + r;
    if (row < N) {
      ushort4 ov;
      ov.x = f2bf(acc[r][0]); ov.y = f2bf(acc[r][1]);
      ov.z = f2bf(acc[r][2]); ov.w = f2bf(acc[r][3]);
      reinterpret_cast<ushort4*>(h2b + (size_t)row * 64)[ct] = ov;
    }
  }
}

// ---- gather2: bf16, half-wave per edge, 4-edge chunks per half ----
__global__ __launch_bounds__(256) void gather2w_kernel(
    const unsigned short* __restrict__ h2b, const float* __restrict__ w2,
    const float* __restrict__ wself2, const float* __restrict__ winv2,
    const float* __restrict__ b2, const int* __restrict__ row_start,
    const int* __restrict__ csr_src, float* __restrict__ h2, int N) {
  const int lane = threadIdx.x & 63;
  const int v = blockIdx.x * 4 + (threadIdx.x >> 6);
  if (v >= N) return;
  const int half = lane >> 5;   // 0/1: which edge of the pair
  const int cl = lane & 31;     // channels 2cl, 2cl+1
  const int rs = row_start[v], re = row_start[v + 1];
  float ax = 0.f, ay = 0.f;
  if (half == 0) {
    const unsigned int u = reinterpret_cast<const unsigned int*>(h2b + (size_t)v * 64)[cl];
    const float ws = wself2[v];
    ax = ws * bf2f(u & 0xffffu);
    ay = ws * bf2f(u >> 16);
  }
  if (rs < re) {
    const int rl = re - 1;
    int k = rs + half;
    // prime chunk metadata: edges k, k+2, k+4, k+6 (this half's stream)
    int s0 = csr_src[min(k, rl)];
    int s1 = csr_src[min(k + 2, rl)];
    int s2 = csr_src[min(k + 4, rl)];
    int s3 = csr_src[min(k + 6, rl)];
    float t0 = w2[min(k, rl)];
    float t1 = w2[min(k + 2, rl)];
    float t2 = w2[min(k + 4, rl)];
    float t3 = w2[min(k + 6, rl)];
    float y0 = (k     < re) ? t0 : 0.f;
    float y1 = (k + 2 < re) ? t1 : 0.f;
    float y2 = (k + 4 < re) ? t2 : 0.f;
    float y3 = (k + 6 < re) ? t3 : 0.f;
    while (k < re) {
      const int kn = k + 8;
      const unsigned int f0 = reinterpret_cast<const unsigned int*>(h2b + (size_t)s0 * 64)[cl];
      const unsigned int f1 = reinterpret_cast<const unsigned int*>(h2b + (size_t)s1 * 64)[cl];
      const unsigned int f2 = reinterpret_cast<const unsigned int*>(h2b + (size_t)s2 * 64)[cl];
      const unsigned int f3 = reinterpret_cast<const unsigned int*>(h2b + (size_t)s3 * 64)[cl];
      const int kc0 = min(kn, rl), kc1 = min(kn + 2, rl), kc2 = min(kn + 4, rl), kc3 = min(kn + 6, rl);
      const int n0 = csr_src[kc0];
      const int n1 = csr_src[kc1];
      const int n2 = csr_src[kc2];
      const int n3 = csr_src[kc3];
      const float u0 = w2[kc0];
      const float u1 = w2[kc1];
      const float u2 = w2[kc2];
      const float u3 = w2[kc3];
      ax = fmaf(y0, bf2f(f0 & 0xffffu), ax); ay = fmaf(y0, bf2f(f0 >> 16), ay);
      ax = fmaf(y1, bf2f(f1 & 0xffffu), ax); ay = fmaf(y1, bf2f(f1 >> 16), ay);
      ax = fmaf(y2, bf2f(f2 & 0xffffu), ax); ay = fmaf(y2, bf2f(f2 >> 16), ay);
      ax = fmaf(y3, bf2f(f3 & 0xffffu), ax); ay = fmaf(y3, bf2f(f3 >> 16), ay);
      s0 = n0; s1 = n1; s2 = n2; s3 = n3;
      y0 = (kn     < re) ? u0 : 0.f;
      y1 = (kn + 2 < re) ? u1 : 0.f;
      y2 = (kn + 4 < re) ? u2 : 0.f;
      y3 = (kn + 6 < re) ? u3 : 0.f;
      k = kn;
    }
  }
  ax += __shfl_xor(ax, 32, 64);
  ay += __shfl_xor(ay, 32, 64);
  if (half == 0) {
    const float wi = winv2[v];
    float2 o;
    o.x = elu1(ax * wi + b2[2 * cl]);
    o.y = elu1(ay * wi + b2[2 * cl + 1]);
    reinterpret_cast<float2*>(h2 + (size_t)v * 64)[cl] = o;
  }
}

// ---------------- mean-pool over sorted batch ----------------
__global__ __launch_bounds__(256) void pool_kernel(
    const float* __restrict__ h2, const int* __restrict__ batch,
    float* __restrict__ pooled, float* __restrict__ cntf, int N) {
  const int lane = threadIdx.x & 63;
  const int gw = blockIdx.x * 4 + (threadIdx.x >> 6);
  const int s = gw * 64;
  if (s >= N) return;
  const int e = min(s + 64, N);
  int cur = batch[s];
  float racc = 0.f;
  int rc = 0;
  for (int v = s; v < e; v++) {
    const int g = batch[v];
    if (g != cur) {
      atomicAdd(&pooled[(size_t)cur * 64 + lane], racc);
      if (lane == 0) atomicAdd(&cntf[cur], (float)rc);
      racc = 0.f; rc = 0; cur = g;
    }
    racc += h2[(size_t)v * 64 + lane];
    rc++;
  }
  atomicAdd(&pooled[(size_t)cur * 64 + lane], racc);
  if (lane == 0) atomicAdd(&cntf[cur], (float)rc);
}

// ---------------- classifier ----------------
__global__ __launch_bounds__(64) void final_kernel(
    const float* __restrict__ pooled, const float* __restrict__ cntf,
    const float* __restrict__ Wc, const float* __restrict__ bc, float* __restrict__ out) {
  const int g = threadIdx.x;
  float acc = 0.f;
  for (int c = 0; c < 64; c++) acc = fmaf(pooled[(size_t)g * 64 + c], Wc[c], acc);
  const float cnt = fmaxf(cntf[g], 1.0f);
  out[g] = acc / cnt + bc[0];
}

extern "C" void kernel_launch(void* const* d_in, const int* in_sizes, int n_in,
                              void* d_out, int out_size, void* d_ws, size_t ws_size,
                              hipStream_t stream) {
  const float* x     = (const float*)d_in[0];
  const int*   ei    = (const int*)d_in[1];
  const int*   batch = (const int*)d_in[2];
  const float* W1    = (const float*)d_in[3];
  const float* atts1 = (const float*)d_in[4];
  const float* attd1 = (const float*)d_in[5];
  const float* b1    = (const float*)d_in[6];
  const float* W2    = (const float*)d_in[7];
  const float* atts2 = (const float*)d_in[8];
  const float* attd2 = (const float*)d_in[9];
  const float* b2    = (const float*)d_in[10];
  const float* Wc    = (const float*)d_in[11];
  const float* bc    = (const float*)d_in[12];
  float* out = (float*)d_out;

  const int N = in_sizes[0] / IN_F;   // 50000
  const int E = in_sizes[1] / 2;      // 800000
  const int* src = ei;
  const int* dst = ei + E;
  const int NB = (N + 255) / 256;     // scan blocks

  char* ws = (char*)d_ws;
  size_t off = 0;
  auto take = [&](size_t bytes) -> void* {
    void* p = ws + off;
    off = (off + bytes + 255) & ~(size_t)255;
    return p;
  };
  unsigned short* h1b   = (unsigned short*)take((size_t)N * 256 * 2);
  unsigned short* hmidb = (unsigned short*)take((size_t)N * 256 * 2);
  unsigned short* h2b   = (unsigned short*)take((size_t)N * 64 * 2);
  float* as1      = (float*)take((size_t)N * 4 * sizeof(float));
  float* ad1      = (float*)take((size_t)N * 4 * sizeof(float));
  float* as2      = (float*)take((size_t)N * sizeof(float));
  float* ad2      = (float*)take((size_t)N * sizeof(float));
  int*   cnt      = (int*)take((size_t)N * sizeof(int));
  int*   row_start= (int*)take((size_t)(N + 1) * sizeof(int));
  int*   cursor   = (int*)take((size_t)N * sizeof(int));
  int*   csr_src  = (int*)take((size_t)E * sizeof(int));
  int*   bsum     = (int*)take((size_t)NB * sizeof(int));
  int*   boff     = (int*)take((size_t)NB * sizeof(int));
  float* pooled   = (float*)take((size_t)GROUPS * 64 * sizeof(float));
  float* cntf     = (float*)take((size_t)GROUPS * sizeof(float));
  float* w1       = (float*)take((size_t)E * 4 * sizeof(float));
  float* wself1   = (float*)take((size_t)N * 4 * sizeof(float));
  float* winv1    = (float*)take((size_t)N * 4 * sizeof(float));
  float* h2       = (float*)take((size_t)N * 64 * sizeof(float));
  // conv2 edge buffers alias conv1's (dead after gather1w)
  float* w2     = w1;
  float* wself2 = wself1;
  float* winv2  = winv1;

  hipMemsetAsync(cnt, 0, (size_t)N * sizeof(int), stream);
  hipMemsetAsync(pooled, 0, (size_t)GROUPS * 64 * sizeof(float), stream);
  hipMemsetAsync(cntf, 0, (size_t)GROUPS * sizeof(float), stream);

  // conv1 linear + fused attention coefficients
  gemm1_kernel<<<(N + 31) / 32, 256, 0, stream>>>(x, W1, atts1, attd1, h1b, as1, ad1, N);

  // CSR by dst (multi-block scan)
  hist_kernel<<<(E + 255) / 256, 256, 0, stream>>>(dst, cnt, E);
  block_reduce_kernel<<<NB, 256, 0, stream>>>(cnt, bsum, N);
  bsum_scan_kernel<<<1, 256, 0, stream>>>(bsum, boff, NB);
  block_scan_kernel<<<NB, 256, 0, stream>>>(cnt, boff, row_start, cursor, N);
  scatter_kernel<<<(E + 255) / 256, 256, 0, stream>>>(src, dst, cursor, csr_src, E);

  // conv1: edge weights then pure gather
  edge_w1_kernel<<<(N + 3) / 4, 256, 0, stream>>>(as1, ad1, row_start, csr_src, w1, wself1, winv1, N);
  gather1w_kernel<<<(N + 3) / 4, 256, 0, stream>>>(h1b, w1, wself1, winv1, b1, row_start, csr_src, hmidb, N);

  // conv2
  gemm2_kernel<<<(N + 31) / 32, 256, 0, stream>>>(hmidb, W2, atts2, attd2, h2b, as2, ad2, N);
  edge_w2_kernel<<<(N + 3) / 4, 256, 0, stream>>>(as2, ad2, row_start, csr_src, w2, wself2, winv2, N);
  gather2w_kernel<<<(N + 3) / 4, 256, 0, stream>>>(h2b, w2, wself2, winv2, b2, row_start, csr_src, h2, N);

  // pooling + classifier
  pool_kernel<<<((N + 63) / 64 + 3) / 4, 256, 0, stream>>>(h2, batch, pooled, cntf, N);
  final_kernel<<<1, 64, 0, stream>>>(pooled, cntf, Wc, bc, out);

  (void)n_in; (void)out_size; (void)ws_size;
}

// Round 6
// 369.676 us; speedup vs baseline: 1.8847x; 1.0163x over previous
//
#include <hip/hip_runtime.h>
#include <hip/hip_bf16.h>

constexpr int HEADS  = 4;
constexpr int HID    = 64;
constexpr int IN_F   = 128;
constexpr int GROUPS = 64;
constexpr float NEG_SLOPE = 0.2f;
constexpr float EPS_SM    = 1e-16f;

static __device__ __forceinline__ float lrelu(float x) { return x >= 0.f ? x : NEG_SLOPE * x; }
static __device__ __forceinline__ float elu1(float x)  { return x > 0.f ? x : expm1f(x); }

static __device__ __forceinline__ float bf2f(unsigned int u) {
  union { unsigned int i; float f; } x; x.i = u << 16; return x.f;
}
static __device__ __forceinline__ unsigned short f2bf(float f) {
  union { float f; unsigned int i; } x; x.f = f;
  unsigned int lsb = (x.i >> 16) & 1u;
  x.i += 0x7fffu + lsb;
  return (unsigned short)(x.i >> 16);
}

// ---- GEMM1 + fused alpha1: h1b[N,256](bf16) = x @ W1 ; as1/ad1[N,4] ----
// 64 rows/block, 16 rows/thread: 2x arithmetic intensity vs W1 loads.
__global__ __launch_bounds__(256) void gemm1_kernel(
    const float* __restrict__ x, const float* __restrict__ W1,
    const float* __restrict__ att_s, const float* __restrict__ att_d,
    unsigned short* __restrict__ h1b, float* __restrict__ as1, float* __restrict__ ad1, int N) {
  __shared__ float xs[64][IN_F];
  const int t = threadIdx.x;
  const int row0 = blockIdx.x * 64;
  const int rows = min(64, N - row0);
  {
    const float4* xg = reinterpret_cast<const float4*>(x + (size_t)row0 * IN_F);
    float4* sf = reinterpret_cast<float4*>(&xs[0][0]);
    const int maxf4 = rows * (IN_F / 4);
    for (int i = t; i < 64 * (IN_F / 4); i += 256)
      sf[i] = (i < maxf4) ? xg[i] : make_float4(0.f, 0.f, 0.f, 0.f);
  }
  __syncthreads();
  const int ct = t & 63;   // cols ct*4 .. ct*4+3
  const int rt = t >> 6;   // wave id; rows rt*16 .. rt*16+15
  float acc[16][4];
#pragma unroll
  for (int r = 0; r < 16; r++) { acc[r][0]=0.f; acc[r][1]=0.f; acc[r][2]=0.f; acc[r][3]=0.f; }
  for (int k4 = 0; k4 < IN_F / 4; ++k4) {
    float4 w[4];
#pragma unroll
    for (int kk = 0; kk < 4; kk++)
      w[kk] = *reinterpret_cast<const float4*>(&W1[(size_t)(k4 * 4 + kk) * 256 + ct * 4]);
#pragma unroll
    for (int r = 0; r < 16; r++) {
      const float4 xr = *reinterpret_cast<const float4*>(&xs[rt * 16 + r][k4 * 4]);
#pragma unroll
      for (int kk = 0; kk < 4; kk++) {
        const float a = reinterpret_cast<const float*>(&xr)[kk];
        acc[r][0] = fmaf(a, w[kk].x, acc[r][0]);
        acc[r][1] = fmaf(a, w[kk].y, acc[r][1]);
        acc[r][2] = fmaf(a, w[kk].z, acc[r][2]);
        acc[r][3] = fmaf(a, w[kk].w, acc[r][3]);
      }
    }
  }
  // fused alpha: per-row dots with att vectors, reduced over each head's 16 lanes
  const float4 avs = *reinterpret_cast<const float4*>(&att_s[ct * 4]);
  const float4 avd = *reinterpret_cast<const float4*>(&att_d[ct * 4]);
#pragma unroll
  for (int r = 0; r < 16; r++) {
    float ps = acc[r][0]*avs.x + acc[r][1]*avs.y + acc[r][2]*avs.z + acc[r][3]*avs.w;
    float pd = acc[r][0]*avd.x + acc[r][1]*avd.y + acc[r][2]*avd.z + acc[r][3]*avd.w;
#pragma unroll
    for (int o = 8; o > 0; o >>= 1) {
      ps += __shfl_xor(ps, o, 64);
      pd += __shfl_xor(pd, o, 64);
    }
    if ((ct & 15) == 0) {
      const int h = ct >> 4;
      const int row = row0 + rt * 16 + r;
      if (row < N) { as1[(size_t)row * 4 + h] = ps; ad1[(size_t)row * 4 + h] = pd; }
    }
  }
  // bf16 store
#pragma unroll
  for (int r = 0; r < 16; r++) {
    const int row = row0 + rt * 16 + r;
    if (row < N) {
      ushort4 ov;
      ov.x = f2bf(acc[r][0]); ov.y = f2bf(acc[r][1]);
      ov.z = f2bf(acc[r][2]); ov.w = f2bf(acc[r][3]);
      reinterpret_cast<ushort4*>(h1b + (size_t)row * 256)[ct] = ov;
    }
  }
}

// ---------------- CSR build ----------------
__global__ __launch_bounds__(256) void hist_kernel(const int* __restrict__ dst, int* __restrict__ cnt, int E) {
  const int e = blockIdx.x * 256 + threadIdx.x;
  if (e < E) atomicAdd(&cnt[dst[e]], 1);
}

// multi-block scan phase 1: per-block sums of cnt
__global__ __launch_bounds__(256) void block_reduce_kernel(
    const int* __restrict__ cnt, int* __restrict__ bsum, int N) {
  const int i = blockIdx.x * 256 + threadIdx.x;
  int v = (i < N) ? cnt[i] : 0;
#pragma unroll
  for (int o = 32; o > 0; o >>= 1) v += __shfl_xor(v, o, 64);
  __shared__ int ws_[4];
  if ((threadIdx.x & 63) == 0) ws_[threadIdx.x >> 6] = v;
  __syncthreads();
  if (threadIdx.x == 0)
    bsum[blockIdx.x] = ws_[0] + ws_[1] + ws_[2] + ws_[3];
}

// multi-block scan phase 2: exclusive scan of block sums (single block)
__global__ __launch_bounds__(256) void bsum_scan_kernel(
    int* __restrict__ bsum, int* __restrict__ boff, int NB) {
  __shared__ int sdata[256];
  const int t = threadIdx.x;
  int v = (t < NB) ? bsum[t] : 0;
  sdata[t] = v;
  __syncthreads();
  for (int o = 1; o < 256; o <<= 1) {
    int x = (t >= o) ? sdata[t - o] : 0;
    __syncthreads();
    sdata[t] += x;
    __syncthreads();
  }
  if (t < NB) boff[t] = sdata[t] - v;   // exclusive
}

// multi-block scan phase 3: in-block exclusive scan + offset; write row_start & cursor
__global__ __launch_bounds__(256) void block_scan_kernel(
    const int* __restrict__ cnt, const int* __restrict__ boff,
    int* __restrict__ row_start, int* __restrict__ cursor, int N) {
  __shared__ int sdata[256];
  const int t = threadIdx.x;
  const int i = blockIdx.x * 256 + t;
  int v = (i < N) ? cnt[i] : 0;
  sdata[t] = v;
  __syncthreads();
  for (int o = 1; o < 256; o <<= 1) {
    int x = (t >= o) ? sdata[t - o] : 0;
    __syncthreads();
    sdata[t] += x;
    __syncthreads();
  }
  if (i < N) {
    const int rs = boff[blockIdx.x] + sdata[t] - v;
    row_start[i] = rs;
    cursor[i] = rs;
    if (i == N - 1) row_start[N] = rs + v;
  }
}

__global__ __launch_bounds__(256) void scatter_kernel(
    const int* __restrict__ src, const int* __restrict__ dst,
    int* __restrict__ cursor, int* __restrict__ csr_src, int E) {
  const int e = blockIdx.x * 256 + threadIdx.x;
  if (e < E) {
    const int d = dst[e];
    const int pos = atomicAdd(&cursor[d], 1);
    csr_src[pos] = src[e];
  }
}

// ---------------- edge weights conv1: 2 nodes per wave (32-lane groups) ----------------
__global__ __launch_bounds__(256) void edge_w1_kernel(
    const float* __restrict__ as1, const float* __restrict__ ad1,
    const int* __restrict__ row_start, const int* __restrict__ csr_src,
    float* __restrict__ w1, float* __restrict__ wself, float* __restrict__ winv, int N) {
  const int sl = threadIdx.x & 31;
  const int v = blockIdx.x * 8 + (threadIdx.x >> 5);
  if (v >= N) return;
  const int rs = row_start[v], re = row_start[v + 1];
  const float4 adv = *reinterpret_cast<const float4*>(&ad1[(size_t)v * 4]);
  const float4 asv = *reinterpret_cast<const float4*>(&as1[(size_t)v * 4]);
  const float* adp = reinterpret_cast<const float*>(&adv);
  const float* asp = reinterpret_cast<const float*>(&asv);
  float eself[HEADS], m[HEADS];
#pragma unroll
  for (int h = 0; h < HEADS; h++) { eself[h] = lrelu(asp[h] + adp[h]); m[h] = eself[h]; }
  for (int k = rs + sl; k < re; k += 32) {
    const int s = csr_src[k];
    const float4 av = *reinterpret_cast<const float4*>(&as1[(size_t)s * 4]);
    const float* ap = reinterpret_cast<const float*>(&av);
#pragma unroll
    for (int h = 0; h < HEADS; h++) m[h] = fmaxf(m[h], lrelu(ap[h] + adp[h]));
  }
#pragma unroll
  for (int h = 0; h < HEADS; h++)
#pragma unroll
    for (int o = 16; o > 0; o >>= 1) m[h] = fmaxf(m[h], __shfl_xor(m[h], o, 64));
  float den[HEADS] = {0.f, 0.f, 0.f, 0.f};
  for (int k = rs + sl; k < re; k += 32) {
    const int s = csr_src[k];
    const float4 av = *reinterpret_cast<const float4*>(&as1[(size_t)s * 4]);
    const float* ap = reinterpret_cast<const float*>(&av);
    float4 wv;
    float* wp = reinterpret_cast<float*>(&wv);
#pragma unroll
    for (int h = 0; h < HEADS; h++) {
      const float w = __expf(lrelu(ap[h] + adp[h]) - m[h]);
      wp[h] = w;
      den[h] += w;
    }
    *reinterpret_cast<float4*>(&w1[(size_t)k * 4]) = wv;
  }
#pragma unroll
  for (int h = 0; h < HEADS; h++)
#pragma unroll
    for (int o = 16; o > 0; o >>= 1) den[h] += __shfl_xor(den[h], o, 64);
  if (sl == 0) {
    float4 wsv, wiv;
    float* wsp = reinterpret_cast<float*>(&wsv);
    float* wip = reinterpret_cast<float*>(&wiv);
#pragma unroll
    for (int h = 0; h < HEADS; h++) {
      const float ws_ = __expf(eself[h] - m[h]);
      wsp[h] = ws_;
      wip[h] = 1.f / (den[h] + ws_ + EPS_SM);
    }
    *reinterpret_cast<float4*>(&wself[(size_t)v * 4]) = wsv;
    *reinterpret_cast<float4*>(&winv[(size_t)v * 4]) = wiv;
  }
}

// ---------------- edge weights conv2 (1 head): 2 nodes per wave ----------------
__global__ __launch_bounds__(256) void edge_w2_kernel(
    const float* __restrict__ as2, const float* __restrict__ ad2,
    const int* __restrict__ row_start, const int* __restrict__ csr_src,
    float* __restrict__ w2, float* __restrict__ wself2, float* __restrict__ winv2, int N) {
  const int sl = threadIdx.x & 31;
  const int v = blockIdx.x * 8 + (threadIdx.x >> 5);
  if (v >= N) return;
  const int rs = row_start[v], re = row_start[v + 1];
  const float adv = ad2[v];
  const float eself = lrelu(as2[v] + adv);
  float m = eself;
  for (int k = rs + sl; k < re; k += 32)
    m = fmaxf(m, lrelu(as2[csr_src[k]] + adv));
#pragma unroll
  for (int o = 16; o > 0; o >>= 1) m = fmaxf(m, __shfl_xor(m, o, 64));
  float den = 0.f;
  for (int k = rs + sl; k < re; k += 32) {
    const float w = __expf(lrelu(as2[csr_src[k]] + adv) - m);
    w2[k] = w;
    den += w;
  }
#pragma unroll
  for (int o = 16; o > 0; o >>= 1) den += __shfl_xor(den, o, 64);
  if (sl == 0) {
    const float ws_ = __expf(eself - m);
    wself2[v] = ws_;
    winv2[v] = 1.f / (den + ws_ + EPS_SM);
  }
}

// ---- gather1: bf16 gather, 8-edge chunks, one-chunk-ahead meta prefetch ----
__global__ __launch_bounds__(256) void gather1w_kernel(
    const unsigned short* __restrict__ h1b, const float* __restrict__ w1,
    const float* __restrict__ wself, const float* __restrict__ winv,
    const float* __restrict__ b1, const int* __restrict__ row_start,
    const int* __restrict__ csr_src, unsigned short* __restrict__ hmidb, int N) {
  const int lane = threadIdx.x & 63;
  const int v = blockIdx.x * 4 + (threadIdx.x >> 6);
  if (v >= N) return;
  const int hd = lane >> 4;       // head of this lane's 4 channels
  const int rs = row_start[v], re = row_start[v + 1];
  const float ws = wself[(size_t)v * 4 + hd];
  const ushort4 sv = reinterpret_cast<const ushort4*>(h1b + (size_t)v * 256)[lane];
  float4 acc;
  acc.x = ws * bf2f(sv.x); acc.y = ws * bf2f(sv.y);
  acc.z = ws * bf2f(sv.z); acc.w = ws * bf2f(sv.w);
  if (rs < re) {
    const int rl = re - 1;
    int k = rs;
    int s[8]; float y[8];
#pragma unroll
    for (int j = 0; j < 8; j++) {
      const int kc = min(k + j, rl);
      s[j] = csr_src[kc];
      const float tw = w1[(size_t)kc * 4 + hd];
      y[j] = (k + j < re) ? tw : 0.f;
    }
    while (k < re) {
      const int kn = k + 8;
      ushort4 f[8];
#pragma unroll
      for (int j = 0; j < 8; j++)
        f[j] = reinterpret_cast<const ushort4*>(h1b + (size_t)s[j] * 256)[lane];
      int ns[8]; float nu[8];
#pragma unroll
      for (int j = 0; j < 8; j++) {
        const int kc = min(kn + j, rl);
        ns[j] = csr_src[kc];
        nu[j] = w1[(size_t)kc * 4 + hd];
      }
#pragma unroll
      for (int j = 0; j < 8; j++) {
        acc.x = fmaf(y[j], bf2f(f[j].x), acc.x);
        acc.y = fmaf(y[j], bf2f(f[j].y), acc.y);
        acc.z = fmaf(y[j], bf2f(f[j].z), acc.z);
        acc.w = fmaf(y[j], bf2f(f[j].w), acc.w);
      }
#pragma unroll
      for (int j = 0; j < 8; j++) {
        s[j] = ns[j];
        y[j] = (kn + j < re) ? nu[j] : 0.f;
      }
      k = kn;
    }
  }
  const float wi = winv[(size_t)v * 4 + hd];
  const int c0 = lane * 4;
  const float4 bv = *reinterpret_cast<const float4*>(&b1[c0]);
  ushort4 ov;
  ov.x = f2bf(elu1(acc.x * wi + bv.x));
  ov.y = f2bf(elu1(acc.y * wi + bv.y));
  ov.z = f2bf(elu1(acc.z * wi + bv.z));
  ov.w = f2bf(elu1(acc.w * wi + bv.w));
  reinterpret_cast<ushort4*>(hmidb + (size_t)v * 256)[lane] = ov;
}

// ---- GEMM2 + fused alpha2: h2b[N,64](bf16) = hmidb @ W2 ; as2/ad2[N] ----
__global__ __launch_bounds__(256) void gemm2_kernel(
    const unsigned short* __restrict__ A, const float* __restrict__ W,
    const float* __restrict__ att_s, const float* __restrict__ att_d,
    unsigned short* __restrict__ h2b, float* __restrict__ as2, float* __restrict__ ad2, int N) {
  __shared__ float as_[32][256];
  const int t = threadIdx.x;
  const int row0 = blockIdx.x * 32;
  const int rows = min(32, N - row0);
  {
    const uint4* ag = reinterpret_cast<const uint4*>(A + (size_t)row0 * 256);
    const int maxu4 = rows * 32;
    for (int i = t; i < 32 * 32; i += 256) {
      uint4 u = (i < maxu4) ? ag[i] : make_uint4(0u, 0u, 0u, 0u);
      float* dp = &as_[i >> 5][(i & 31) * 8];
      dp[0] = bf2f(u.x & 0xffffu); dp[1] = bf2f(u.x >> 16);
      dp[2] = bf2f(u.y & 0xffffu); dp[3] = bf2f(u.y >> 16);
      dp[4] = bf2f(u.z & 0xffffu); dp[5] = bf2f(u.z >> 16);
      dp[6] = bf2f(u.w & 0xffffu); dp[7] = bf2f(u.w >> 16);
    }
  }
  __syncthreads();
  const int ct = t & 15;  // cols ct*4..+3
  const int rt = t >> 4;  // rows rt*2..+1
  float acc[2][4] = {{0.f,0.f,0.f,0.f},{0.f,0.f,0.f,0.f}};
  for (int k4 = 0; k4 < 64; ++k4) {
    const float4 xr0 = *reinterpret_cast<const float4*>(&as_[rt * 2][k4 * 4]);
    const float4 xr1 = *reinterpret_cast<const float4*>(&as_[rt * 2 + 1][k4 * 4]);
#pragma unroll
    for (int kk = 0; kk < 4; kk++) {
      const float4 w = *reinterpret_cast<const float4*>(&W[(size_t)(k4 * 4 + kk) * 64 + ct * 4]);
      const float a0 = reinterpret_cast<const float*>(&xr0)[kk];
      const float a1 = reinterpret_cast<const float*>(&xr1)[kk];
      acc[0][0] = fmaf(a0, w.x, acc[0][0]); acc[0][1] = fmaf(a0, w.y, acc[0][1]);
      acc[0][2] = fmaf(a0, w.z, acc[0][2]); acc[0][3] = fmaf(a0, w.w, acc[0][3]);
      acc[1][0] = fmaf(a1, w.x, acc[1][0]); acc[1][1] = fmaf(a1, w.y, acc[1][1]);
      acc[1][2] = fmaf(a1, w.z, acc[1][2]); acc[1][3] = fmaf(a1, w.w, acc[1][3]);
    }
  }
  // fused alpha2: dot over 64 cols, reduce across the 16 ct lanes
  const float4 avs = *reinterpret_cast<const float4*>(&att_s[ct * 4]);
  const float4 avd = *reinterpret_cast<const float4*>(&att_d[ct * 4]);
  float ps[2], pd[2];
#pragma unroll
  for (int r = 0; r < 2; r++) {
    ps[r] = acc[r][0]*avs.x + acc[r][1]*avs.y + acc[r][2]*avs.z + acc[r][3]*avs.w;
    pd[r] = acc[r][0]*avd.x + acc[r][1]*avd.y + acc[r][2]*avd.z + acc[r][3]*avd.w;
#pragma unroll
    for (int o = 8; o > 0; o >>= 1) {
      ps[r] += __shfl_xor(ps[r], o, 64);
      pd[r] += __shfl_xor(pd[r], o, 64);
    }
  }
  if (((t & 63) & 15) == 0) {
#pragma unroll
    for (int r = 0; r < 2; r++) {
      const int row = row0 + rt * 2 + r;
      if (row < N) { as2[row] = ps[r]; ad2[row] = pd[r]; }
    }
  }
#pragma unroll
  for (int r = 0; r < 2; r++) {
    const int row = row0 + rt * 2 + r;
    if (row < N) {
      ushort4 ov;
      ov.x = f2bf(acc[r][0]); ov.y = f2bf(acc[r][1]);
      ov.z = f2bf(acc[r][2]); ov.w = f2bf(acc[r][3]);
      reinterpret_cast<ushort4*>(h2b + (size_t)row * 64)[ct] = ov;
    }
  }
}

// ---- gather2: bf16, half-wave per edge, 4-edge chunks per half ----
__global__ __launch_bounds__(256) void gather2w_kernel(
    const unsigned short* __restrict__ h2b, const float* __restrict__ w2,
    const float* __restrict__ wself2, const float* __restrict__ winv2,
    const float* __restrict__ b2, const int* __restrict__ row_start,
    const int* __restrict__ csr_src, float* __restrict__ h2, int N) {
  const int lane = threadIdx.x & 63;
  const int v = blockIdx.x * 4 + (threadIdx.x >> 6);
  if (v >= N) return;
  const int half = lane >> 5;   // 0/1: which edge of the pair
  const int cl = lane & 31;     // channels 2cl, 2cl+1
  const int rs = row_start[v], re = row_start[v + 1];
  float ax = 0.f, ay = 0.f;
  if (half == 0) {
    const unsigned int u = reinterpret_cast<const unsigned int*>(h2b + (size_t)v * 64)[cl];
    const float ws = wself2[v];
    ax = ws * bf2f(u & 0xffffu);
    ay = ws * bf2f(u >> 16);
  }
  if (rs < re) {
    const int rl = re - 1;
    int k = rs + half;
    int s0 = csr_src[min(k, rl)];
    int s1 = csr_src[min(k + 2, rl)];
    int s2 = csr_src[min(k + 4, rl)];
    int s3 = csr_src[min(k + 6, rl)];
    float t0 = w2[min(k, rl)];
    float t1 = w2[min(k + 2, rl)];
    float t2 = w2[min(k + 4, rl)];
    float t3 = w2[min(k + 6, rl)];
    float y0 = (k     < re) ? t0 : 0.f;
    float y1 = (k + 2 < re) ? t1 : 0.f;
    float y2 = (k + 4 < re) ? t2 : 0.f;
    float y3 = (k + 6 < re) ? t3 : 0.f;
    while (k < re) {
      const int kn = k + 8;
      const unsigned int f0 = reinterpret_cast<const unsigned int*>(h2b + (size_t)s0 * 64)[cl];
      const unsigned int f1 = reinterpret_cast<const unsigned int*>(h2b + (size_t)s1 * 64)[cl];
      const unsigned int f2 = reinterpret_cast<const unsigned int*>(h2b + (size_t)s2 * 64)[cl];
      const unsigned int f3 = reinterpret_cast<const unsigned int*>(h2b + (size_t)s3 * 64)[cl];
      const int kc0 = min(kn, rl), kc1 = min(kn + 2, rl), kc2 = min(kn + 4, rl), kc3 = min(kn + 6, rl);
      const int n0 = csr_src[kc0];
      const int n1 = csr_src[kc1];
      const int n2 = csr_src[kc2];
      const int n3 = csr_src[kc3];
      const float u0 = w2[kc0];
      const float u1 = w2[kc1];
      const float u2 = w2[kc2];
      const float u3 = w2[kc3];
      ax = fmaf(y0, bf2f(f0 & 0xffffu), ax); ay = fmaf(y0, bf2f(f0 >> 16), ay);
      ax = fmaf(y1, bf2f(f1 & 0xffffu), ax); ay = fmaf(y1, bf2f(f1 >> 16), ay);
      ax = fmaf(y2, bf2f(f2 & 0xffffu), ax); ay = fmaf(y2, bf2f(f2 >> 16), ay);
      ax = fmaf(y3, bf2f(f3 & 0xffffu), ax); ay = fmaf(y3, bf2f(f3 >> 16), ay);
      s0 = n0; s1 = n1; s2 = n2; s3 = n3;
      y0 = (kn     < re) ? u0 : 0.f;
      y1 = (kn + 2 < re) ? u1 : 0.f;
      y2 = (kn + 4 < re) ? u2 : 0.f;
      y3 = (kn + 6 < re) ? u3 : 0.f;
      k = kn;
    }
  }
  ax += __shfl_xor(ax, 32, 64);
  ay += __shfl_xor(ay, 32, 64);
  if (half == 0) {
    const float wi = winv2[v];
    float2 o;
    o.x = elu1(ax * wi + b2[2 * cl]);
    o.y = elu1(ay * wi + b2[2 * cl + 1]);
    reinterpret_cast<float2*>(h2 + (size_t)v * 64)[cl] = o;
  }
}

// ---------------- mean-pool over sorted batch ----------------
__global__ __launch_bounds__(256) void pool_kernel(
    const float* __restrict__ h2, const int* __restrict__ batch,
    float* __restrict__ pooled, float* __restrict__ cntf, int N) {
  const int lane = threadIdx.x & 63;
  const int gw = blockIdx.x * 4 + (threadIdx.x >> 6);
  const int s = gw * 64;
  if (s >= N) return;
  const int e = min(s + 64, N);
  int cur = batch[s];
  float racc = 0.f;
  int rc = 0;
  for (int v = s; v < e; v++) {
    const int g = batch[v];
    if (g != cur) {
      atomicAdd(&pooled[(size_t)cur * 64 + lane], racc);
      if (lane == 0) atomicAdd(&cntf[cur], (float)rc);
      racc = 0.f; rc = 0; cur = g;
    }
    racc += h2[(size_t)v * 64 + lane];
    rc++;
  }
  atomicAdd(&pooled[(size_t)cur * 64 + lane], racc);
  if (lane == 0) atomicAdd(&cntf[cur], (float)rc);
}

// ---------------- classifier ----------------
__global__ __launch_bounds__(64) void final_kernel(
    const float* __restrict__ pooled, const float* __restrict__ cntf,
    const float* __restrict__ Wc, const float* __restrict__ bc, float* __restrict__ out) {
  const int g = threadIdx.x;
  float acc = 0.f;
  for (int c = 0; c < 64; c++) acc = fmaf(pooled[(size_t)g * 64 + c], Wc[c], acc);
  const float cnt = fmaxf(cntf[g], 1.0f);
  out[g] = acc / cnt + bc[0];
}

extern "C" void kernel_launch(void* const* d_in, const int* in_sizes, int n_in,
                              void* d_out, int out_size, void* d_ws, size_t ws_size,
                              hipStream_t stream) {
  const float* x     = (const float*)d_in[0];
  const int*   ei    = (const int*)d_in[1];
  const int*   batch = (const int*)d_in[2];
  const float* W1    = (const float*)d_in[3];
  const float* atts1 = (const float*)d_in[4];
  const float* attd1 = (const float*)d_in[5];
  const float* b1    = (const float*)d_in[6];
  const float* W2    = (const float*)d_in[7];
  const float* atts2 = (const float*)d_in[8];
  const float* attd2 = (const float*)d_in[9];
  const float* b2    = (const float*)d_in[10];
  const float* Wc    = (const float*)d_in[11];
  const float* bc    = (const float*)d_in[12];
  float* out = (float*)d_out;

  const int N = in_sizes[0] / IN_F;   // 50000
  const int E = in_sizes[1] / 2;      // 800000
  const int* src = ei;
  const int* dst = ei + E;
  const int NB = (N + 255) / 256;     // scan blocks

  char* ws = (char*)d_ws;
  size_t off = 0;
  auto take = [&](size_t bytes) -> void* {
    void* p = ws + off;
    off = (off + bytes + 255) & ~(size_t)255;
    return p;
  };
  unsigned short* h1b   = (unsigned short*)take((size_t)N * 256 * 2);
  unsigned short* hmidb = (unsigned short*)take((size_t)N * 256 * 2);
  unsigned short* h2b   = (unsigned short*)take((size_t)N * 64 * 2);
  float* as1      = (float*)take((size_t)N * 4 * sizeof(float));
  float* ad1      = (float*)take((size_t)N * 4 * sizeof(float));
  float* as2      = (float*)take((size_t)N * sizeof(float));
  float* ad2      = (float*)take((size_t)N * sizeof(float));
  int*   cnt      = (int*)take((size_t)N * sizeof(int));
  int*   row_start= (int*)take((size_t)(N + 1) * sizeof(int));
  int*   cursor   = (int*)take((size_t)N * sizeof(int));
  int*   csr_src  = (int*)take((size_t)E * sizeof(int));
  int*   bsum     = (int*)take((size_t)NB * sizeof(int));
  int*   boff     = (int*)take((size_t)NB * sizeof(int));
  float* pooled   = (float*)take((size_t)GROUPS * 64 * sizeof(float));
  float* cntf     = (float*)take((size_t)GROUPS * sizeof(float));
  float* w1       = (float*)take((size_t)E * 4 * sizeof(float));
  float* wself1   = (float*)take((size_t)N * 4 * sizeof(float));
  float* winv1    = (float*)take((size_t)N * 4 * sizeof(float));
  float* h2       = (float*)take((size_t)N * 64 * sizeof(float));
  // conv2 edge buffers alias conv1's (dead after gather1w)
  float* w2     = w1;
  float* wself2 = wself1;
  float* winv2  = winv1;

  hipMemsetAsync(cnt, 0, (size_t)N * sizeof(int), stream);
  hipMemsetAsync(pooled, 0, (size_t)GROUPS * 64 * sizeof(float), stream);
  hipMemsetAsync(cntf, 0, (size_t)GROUPS * sizeof(float), stream);

  // conv1 linear + fused attention coefficients
  gemm1_kernel<<<(N + 63) / 64, 256, 0, stream>>>(x, W1, atts1, attd1, h1b, as1, ad1, N);

  // CSR by dst (multi-block scan)
  hist_kernel<<<(E + 255) / 256, 256, 0, stream>>>(dst, cnt, E);
  block_reduce_kernel<<<NB, 256, 0, stream>>>(cnt, bsum, N);
  bsum_scan_kernel<<<1, 256, 0, stream>>>(bsum, boff, NB);
  block_scan_kernel<<<NB, 256, 0, stream>>>(cnt, boff, row_start, cursor, N);
  scatter_kernel<<<(E + 255) / 256, 256, 0, stream>>>(src, dst, cursor, csr_src, E);

  // conv1: edge weights then pure gather
  edge_w1_kernel<<<(N + 7) / 8, 256, 0, stream>>>(as1, ad1, row_start, csr_src, w1, wself1, winv1, N);
  gather1w_kernel<<<(N + 3) / 4, 256, 0, stream>>>(h1b, w1, wself1, winv1, b1, row_start, csr_src, hmidb, N);

  // conv2
  gemm2_kernel<<<(N + 31) / 32, 256, 0, stream>>>(hmidb, W2, atts2, attd2, h2b, as2, ad2, N);
  edge_w2_kernel<<<(N + 7) / 8, 256, 0, stream>>>(as2, ad2, row_start, csr_src, w2, wself2, winv2, N);
  gather2w_kernel<<<(N + 3) / 4, 256, 0, stream>>>(h2b, w2, wself2, winv2, b2, row_start, csr_src, h2, N);

  // pooling + classifier
  pool_kernel<<<((N + 63) / 64 + 3) / 4, 256, 0, stream>>>(h2, batch, pooled, cntf, N);
  final_kernel<<<1, 64, 0, stream>>>(pooled, cntf, Wc, bc, out);

  (void)n_in; (void)out_size; (void)ws_size;
}

// Round 7
// 367.121 us; speedup vs baseline: 1.8978x; 1.0070x over previous
//
#include <hip/hip_runtime.h>
#include <hip/hip_bf16.h>

constexpr int HEADS  = 4;
constexpr int HID    = 64;
constexpr int IN_F   = 128;
constexpr int GROUPS = 64;
constexpr float NEG_SLOPE = 0.2f;
constexpr float EPS_SM    = 1e-16f;

static __device__ __forceinline__ float lrelu(float x) { return x >= 0.f ? x : NEG_SLOPE * x; }
static __device__ __forceinline__ float elu1(float x)  { return x > 0.f ? x : expm1f(x); }

static __device__ __forceinline__ float bf2f(unsigned int u) {
  union { unsigned int i; float f; } x; x.i = u << 16; return x.f;
}
static __device__ __forceinline__ unsigned short f2bf(float f) {
  union { float f; unsigned int i; } x; x.f = f;
  unsigned int lsb = (x.i >> 16) & 1u;
  x.i += 0x7fffu + lsb;
  return (unsigned short)(x.i >> 16);
}

// ---- GEMM1 + fused alpha1: h1b[N,256](bf16) = x @ W1 ; as1/ad1[N,4] ----
// 512 threads, 64 rows/block, 8 rows/thread: 2x W1 reuse at full occupancy.
__global__ __launch_bounds__(512) void gemm1_kernel(
    const float* __restrict__ x, const float* __restrict__ W1,
    const float* __restrict__ att_s, const float* __restrict__ att_d,
    unsigned short* __restrict__ h1b, float* __restrict__ as1, float* __restrict__ ad1, int N) {
  __shared__ float xs[64][IN_F];
  const int t = threadIdx.x;
  const int row0 = blockIdx.x * 64;
  const int rows = min(64, N - row0);
  {
    const float4* xg = reinterpret_cast<const float4*>(x + (size_t)row0 * IN_F);
    float4* sf = reinterpret_cast<float4*>(&xs[0][0]);
    const int maxf4 = rows * (IN_F / 4);
    for (int i = t; i < 64 * (IN_F / 4); i += 512)
      sf[i] = (i < maxf4) ? xg[i] : make_float4(0.f, 0.f, 0.f, 0.f);
  }
  __syncthreads();
  const int ct = t & 63;   // cols ct*4 .. ct*4+3
  const int rt = t >> 6;   // wave id 0..7; rows rt*8 .. rt*8+7
  float acc[8][4];
#pragma unroll
  for (int r = 0; r < 8; r++) { acc[r][0]=0.f; acc[r][1]=0.f; acc[r][2]=0.f; acc[r][3]=0.f; }
  for (int k4 = 0; k4 < IN_F / 4; ++k4) {
    float4 xr[8];
#pragma unroll
    for (int r = 0; r < 8; r++)
      xr[r] = *reinterpret_cast<const float4*>(&xs[rt * 8 + r][k4 * 4]);
#pragma unroll
    for (int kk = 0; kk < 4; kk++) {
      const float4 w = *reinterpret_cast<const float4*>(&W1[(size_t)(k4 * 4 + kk) * 256 + ct * 4]);
#pragma unroll
      for (int r = 0; r < 8; r++) {
        const float a = reinterpret_cast<const float*>(&xr[r])[kk];
        acc[r][0] = fmaf(a, w.x, acc[r][0]);
        acc[r][1] = fmaf(a, w.y, acc[r][1]);
        acc[r][2] = fmaf(a, w.z, acc[r][2]);
        acc[r][3] = fmaf(a, w.w, acc[r][3]);
      }
    }
  }
  // fused alpha: per-row dots with att vectors, reduced over each head's 16 lanes
  const float4 avs = *reinterpret_cast<const float4*>(&att_s[ct * 4]);
  const float4 avd = *reinterpret_cast<const float4*>(&att_d[ct * 4]);
#pragma unroll
  for (int r = 0; r < 8; r++) {
    float ps = acc[r][0]*avs.x + acc[r][1]*avs.y + acc[r][2]*avs.z + acc[r][3]*avs.w;
    float pd = acc[r][0]*avd.x + acc[r][1]*avd.y + acc[r][2]*avd.z + acc[r][3]*avd.w;
#pragma unroll
    for (int o = 8; o > 0; o >>= 1) {
      ps += __shfl_xor(ps, o, 64);
      pd += __shfl_xor(pd, o, 64);
    }
    if ((ct & 15) == 0) {
      const int h = ct >> 4;
      const int row = row0 + rt * 8 + r;
      if (row < N) { as1[(size_t)row * 4 + h] = ps; ad1[(size_t)row * 4 + h] = pd; }
    }
  }
  // bf16 store
#pragma unroll
  for (int r = 0; r < 8; r++) {
    const int row = row0 + rt * 8 + r;
    if (row < N) {
      ushort4 ov;
      ov.x = f2bf(acc[r][0]); ov.y = f2bf(acc[r][1]);
      ov.z = f2bf(acc[r][2]); ov.w = f2bf(acc[r][3]);
      reinterpret_cast<ushort4*>(h1b + (size_t)row * 256)[ct] = ov;
    }
  }
}

// ---------------- CSR build ----------------
__global__ __launch_bounds__(256) void hist_kernel(const int* __restrict__ dst, int* __restrict__ cnt, int E) {
  const int e = blockIdx.x * 256 + threadIdx.x;
  if (e < E) atomicAdd(&cnt[dst[e]], 1);
}

// multi-block scan phase 1: per-block sums of cnt
__global__ __launch_bounds__(256) void block_reduce_kernel(
    const int* __restrict__ cnt, int* __restrict__ bsum, int N) {
  const int i = blockIdx.x * 256 + threadIdx.x;
  int v = (i < N) ? cnt[i] : 0;
#pragma unroll
  for (int o = 32; o > 0; o >>= 1) v += __shfl_xor(v, o, 64);
  __shared__ int ws_[4];
  if ((threadIdx.x & 63) == 0) ws_[threadIdx.x >> 6] = v;
  __syncthreads();
  if (threadIdx.x == 0)
    bsum[blockIdx.x] = ws_[0] + ws_[1] + ws_[2] + ws_[3];
}

// multi-block scan phase 2: exclusive scan of block sums (single block)
__global__ __launch_bounds__(256) void bsum_scan_kernel(
    int* __restrict__ bsum, int* __restrict__ boff, int NB) {
  __shared__ int sdata[256];
  const int t = threadIdx.x;
  int v = (t < NB) ? bsum[t] : 0;
  sdata[t] = v;
  __syncthreads();
  for (int o = 1; o < 256; o <<= 1) {
    int x = (t >= o) ? sdata[t - o] : 0;
    __syncthreads();
    sdata[t] += x;
    __syncthreads();
  }
  if (t < NB) boff[t] = sdata[t] - v;   // exclusive
}

// multi-block scan phase 3: in-block exclusive scan + offset; write row_start & cursor
__global__ __launch_bounds__(256) void block_scan_kernel(
    const int* __restrict__ cnt, const int* __restrict__ boff,
    int* __restrict__ row_start, int* __restrict__ cursor, int N) {
  __shared__ int sdata[256];
  const int t = threadIdx.x;
  const int i = blockIdx.x * 256 + t;
  int v = (i < N) ? cnt[i] : 0;
  sdata[t] = v;
  __syncthreads();
  for (int o = 1; o < 256; o <<= 1) {
    int x = (t >= o) ? sdata[t - o] : 0;
    __syncthreads();
    sdata[t] += x;
    __syncthreads();
  }
  if (i < N) {
    const int rs = boff[blockIdx.x] + sdata[t] - v;
    row_start[i] = rs;
    cursor[i] = rs;
    if (i == N - 1) row_start[N] = rs + v;
  }
}

__global__ __launch_bounds__(256) void scatter_kernel(
    const int* __restrict__ src, const int* __restrict__ dst,
    int* __restrict__ cursor, int* __restrict__ csr_src, int E) {
  const int e = blockIdx.x * 256 + threadIdx.x;
  if (e < E) {
    const int d = dst[e];
    const int pos = atomicAdd(&cursor[d], 1);
    csr_src[pos] = src[e];
  }
}

// ---------------- edge weights conv1: 2 nodes per wave (32-lane groups) ----------------
__global__ __launch_bounds__(256) void edge_w1_kernel(
    const float* __restrict__ as1, const float* __restrict__ ad1,
    const int* __restrict__ row_start, const int* __restrict__ csr_src,
    float* __restrict__ w1, float* __restrict__ wself, float* __restrict__ winv, int N) {
  const int sl = threadIdx.x & 31;
  const int v = blockIdx.x * 8 + (threadIdx.x >> 5);
  if (v >= N) return;
  const int rs = row_start[v], re = row_start[v + 1];
  const float4 adv = *reinterpret_cast<const float4*>(&ad1[(size_t)v * 4]);
  const float4 asv = *reinterpret_cast<const float4*>(&as1[(size_t)v * 4]);
  const float* adp = reinterpret_cast<const float*>(&adv);
  const float* asp = reinterpret_cast<const float*>(&asv);
  float eself[HEADS], m[HEADS];
#pragma unroll
  for (int h = 0; h < HEADS; h++) { eself[h] = lrelu(asp[h] + adp[h]); m[h] = eself[h]; }
  for (int k = rs + sl; k < re; k += 32) {
    const int s = csr_src[k];
    const float4 av = *reinterpret_cast<const float4*>(&as1[(size_t)s * 4]);
    const float* ap = reinterpret_cast<const float*>(&av);
#pragma unroll
    for (int h = 0; h < HEADS; h++) m[h] = fmaxf(m[h], lrelu(ap[h] + adp[h]));
  }
#pragma unroll
  for (int h = 0; h < HEADS; h++)
#pragma unroll
    for (int o = 16; o > 0; o >>= 1) m[h] = fmaxf(m[h], __shfl_xor(m[h], o, 64));
  float den[HEADS] = {0.f, 0.f, 0.f, 0.f};
  for (int k = rs + sl; k < re; k += 32) {
    const int s = csr_src[k];
    const float4 av = *reinterpret_cast<const float4*>(&as1[(size_t)s * 4]);
    const float* ap = reinterpret_cast<const float*>(&av);
    float4 wv;
    float* wp = reinterpret_cast<float*>(&wv);
#pragma unroll
    for (int h = 0; h < HEADS; h++) {
      const float w = __expf(lrelu(ap[h] + adp[h]) - m[h]);
      wp[h] = w;
      den[h] += w;
    }
    *reinterpret_cast<float4*>(&w1[(size_t)k * 4]) = wv;
  }
#pragma unroll
  for (int h = 0; h < HEADS; h++)
#pragma unroll
    for (int o = 16; o > 0; o >>= 1) den[h] += __shfl_xor(den[h], o, 64);
  if (sl == 0) {
    float4 wsv, wiv;
    float* wsp = reinterpret_cast<float*>(&wsv);
    float* wip = reinterpret_cast<float*>(&wiv);
#pragma unroll
    for (int h = 0; h < HEADS; h++) {
      const float ws_ = __expf(eself[h] - m[h]);
      wsp[h] = ws_;
      wip[h] = 1.f / (den[h] + ws_ + EPS_SM);
    }
    *reinterpret_cast<float4*>(&wself[(size_t)v * 4]) = wsv;
    *reinterpret_cast<float4*>(&winv[(size_t)v * 4]) = wiv;
  }
}

// ---------------- edge weights conv2 (1 head): 2 nodes per wave ----------------
__global__ __launch_bounds__(256) void edge_w2_kernel(
    const float* __restrict__ as2, const float* __restrict__ ad2,
    const int* __restrict__ row_start, const int* __restrict__ csr_src,
    float* __restrict__ w2, float* __restrict__ wself2, float* __restrict__ winv2, int N) {
  const int sl = threadIdx.x & 31;
  const int v = blockIdx.x * 8 + (threadIdx.x >> 5);
  if (v >= N) return;
  const int rs = row_start[v], re = row_start[v + 1];
  const float adv = ad2[v];
  const float eself = lrelu(as2[v] + adv);
  float m = eself;
  for (int k = rs + sl; k < re; k += 32)
    m = fmaxf(m, lrelu(as2[csr_src[k]] + adv));
#pragma unroll
  for (int o = 16; o > 0; o >>= 1) m = fmaxf(m, __shfl_xor(m, o, 64));
  float den = 0.f;
  for (int k = rs + sl; k < re; k += 32) {
    const float w = __expf(lrelu(as2[csr_src[k]] + adv) - m);
    w2[k] = w;
    den += w;
  }
#pragma unroll
  for (int o = 16; o > 0; o >>= 1) den += __shfl_xor(den, o, 64);
  if (sl == 0) {
    const float ws_ = __expf(eself - m);
    wself2[v] = ws_;
    winv2[v] = 1.f / (den + ws_ + EPS_SM);
  }
}

// ---- gather1: bf16 gather, 4-edge chunks, one-chunk-ahead meta prefetch ----
__global__ __launch_bounds__(256) void gather1w_kernel(
    const unsigned short* __restrict__ h1b, const float* __restrict__ w1,
    const float* __restrict__ wself, const float* __restrict__ winv,
    const float* __restrict__ b1, const int* __restrict__ row_start,
    const int* __restrict__ csr_src, unsigned short* __restrict__ hmidb, int N) {
  const int lane = threadIdx.x & 63;
  const int v = blockIdx.x * 4 + (threadIdx.x >> 6);
  if (v >= N) return;
  const int hd = lane >> 4;       // head of this lane's 4 channels
  const int rs = row_start[v], re = row_start[v + 1];
  const float ws = wself[(size_t)v * 4 + hd];
  const ushort4 sv = reinterpret_cast<const ushort4*>(h1b + (size_t)v * 256)[lane];
  float4 acc;
  acc.x = ws * bf2f(sv.x); acc.y = ws * bf2f(sv.y);
  acc.z = ws * bf2f(sv.z); acc.w = ws * bf2f(sv.w);
  if (rs < re) {
    const int rl = re - 1;
    int k = rs;
    // prime chunk 0 metadata (clamped indices, zero-masked weights)
    int s0 = csr_src[k];
    int s1 = csr_src[min(k + 1, rl)];
    int s2 = csr_src[min(k + 2, rl)];
    int s3 = csr_src[min(k + 3, rl)];
    float y0 = w1[(size_t)k * 4 + hd];
    float t1 = w1[(size_t)min(k + 1, rl) * 4 + hd];
    float t2 = w1[(size_t)min(k + 2, rl) * 4 + hd];
    float t3 = w1[(size_t)min(k + 3, rl) * 4 + hd];
    float y1 = (k + 1 < re) ? t1 : 0.f;
    float y2 = (k + 2 < re) ? t2 : 0.f;
    float y3 = (k + 3 < re) ? t3 : 0.f;
    while (k < re) {
      const int kn = k + 4;
      // issue 4 independent feature loads
      const ushort4 f0 = reinterpret_cast<const ushort4*>(h1b + (size_t)s0 * 256)[lane];
      const ushort4 f1 = reinterpret_cast<const ushort4*>(h1b + (size_t)s1 * 256)[lane];
      const ushort4 f2 = reinterpret_cast<const ushort4*>(h1b + (size_t)s2 * 256)[lane];
      const ushort4 f3 = reinterpret_cast<const ushort4*>(h1b + (size_t)s3 * 256)[lane];
      // prefetch next chunk metadata (clamped; harmless when past end)
      const int kc0 = min(kn, rl), kc1 = min(kn + 1, rl), kc2 = min(kn + 2, rl), kc3 = min(kn + 3, rl);
      const int n0 = csr_src[kc0];
      const int n1 = csr_src[kc1];
      const int n2 = csr_src[kc2];
      const int n3 = csr_src[kc3];
      const float u0 = w1[(size_t)kc0 * 4 + hd];
      const float u1 = w1[(size_t)kc1 * 4 + hd];
      const float u2 = w1[(size_t)kc2 * 4 + hd];
      const float u3 = w1[(size_t)kc3 * 4 + hd];
      // FMA current chunk
      acc.x = fmaf(y0, bf2f(f0.x), acc.x); acc.y = fmaf(y0, bf2f(f0.y), acc.y);
      acc.z = fmaf(y0, bf2f(f0.z), acc.z); acc.w = fmaf(y0, bf2f(f0.w), acc.w);
      acc.x = fmaf(y1, bf2f(f1.x), acc.x); acc.y = fmaf(y1, bf2f(f1.y), acc.y);
      acc.z = fmaf(y1, bf2f(f1.z), acc.z); acc.w = fmaf(y1, bf2f(f1.w), acc.w);
      acc.x = fmaf(y2, bf2f(f2.x), acc.x); acc.y = fmaf(y2, bf2f(f2.y), acc.y);
      acc.z = fmaf(y2, bf2f(f2.z), acc.z); acc.w = fmaf(y2, bf2f(f2.w), acc.w);
      acc.x = fmaf(y3, bf2f(f3.x), acc.x); acc.y = fmaf(y3, bf2f(f3.y), acc.y);
      acc.z = fmaf(y3, bf2f(f3.z), acc.z); acc.w = fmaf(y3, bf2f(f3.w), acc.w);
      // rotate
      s0 = n0; s1 = n1; s2 = n2; s3 = n3;
      y0 = (kn     < re) ? u0 : 0.f;
      y1 = (kn + 1 < re) ? u1 : 0.f;
      y2 = (kn + 2 < re) ? u2 : 0.f;
      y3 = (kn + 3 < re) ? u3 : 0.f;
      k = kn;
    }
  }
  const float wi = winv[(size_t)v * 4 + hd];
  const int c0 = lane * 4;
  const float4 bv = *reinterpret_cast<const float4*>(&b1[c0]);
  ushort4 ov;
  ov.x = f2bf(elu1(acc.x * wi + bv.x));
  ov.y = f2bf(elu1(acc.y * wi + bv.y));
  ov.z = f2bf(elu1(acc.z * wi + bv.z));
  ov.w = f2bf(elu1(acc.w * wi + bv.w));
  reinterpret_cast<ushort4*>(hmidb + (size_t)v * 256)[lane] = ov;
}

// ---- GEMM2 + fused alpha2: h2b[N,64](bf16) = hmidb @ W2 ; as2/ad2[N] ----
__global__ __launch_bounds__(256) void gemm2_kernel(
    const unsigned short* __restrict__ A, const float* __restrict__ W,
    const float* __restrict__ att_s, const float* __restrict__ att_d,
    unsigned short* __restrict__ h2b, float* __restrict__ as2, float* __restrict__ ad2, int N) {
  __shared__ float as_[32][256];
  const int t = threadIdx.x;
  const int row0 = blockIdx.x * 32;
  const int rows = min(32, N - row0);
  {
    const uint4* ag = reinterpret_cast<const uint4*>(A + (size_t)row0 * 256);
    const int maxu4 = rows * 32;
    for (int i = t; i < 32 * 32; i += 256) {
      uint4 u = (i < maxu4) ? ag[i] : make_uint4(0u, 0u, 0u, 0u);
      float* dp = &as_[i >> 5][(i & 31) * 8];
      dp[0] = bf2f(u.x & 0xffffu); dp[1] = bf2f(u.x >> 16);
      dp[2] = bf2f(u.y & 0xffffu); dp[3] = bf2f(u.y >> 16);
      dp[4] = bf2f(u.z & 0xffffu); dp[5] = bf2f(u.z >> 16);
      dp[6] = bf2f(u.w & 0xffffu); dp[7] = bf2f(u.w >> 16);
    }
  }
  __syncthreads();
  const int ct = t & 15;  // cols ct*4..+3
  const int rt = t >> 4;  // rows rt*2..+1
  float acc[2][4] = {{0.f,0.f,0.f,0.f},{0.f,0.f,0.f,0.f}};
  for (int k4 = 0; k4 < 64; ++k4) {
    const float4 xr0 = *reinterpret_cast<const float4*>(&as_[rt * 2][k4 * 4]);
    const float4 xr1 = *reinterpret_cast<const float4*>(&as_[rt * 2 + 1][k4 * 4]);
#pragma unroll
    for (int kk = 0; kk < 4; kk++) {
      const float4 w = *reinterpret_cast<const float4*>(&W[(size_t)(k4 * 4 + kk) * 64 + ct * 4]);
      const float a0 = reinterpret_cast<const float*>(&xr0)[kk];
      const float a1 = reinterpret_cast<const float*>(&xr1)[kk];
      acc[0][0] = fmaf(a0, w.x, acc[0][0]); acc[0][1] = fmaf(a0, w.y, acc[0][1]);
      acc[0][2] = fmaf(a0, w.z, acc[0][2]); acc[0][3] = fmaf(a0, w.w, acc[0][3]);
      acc[1][0] = fmaf(a1, w.x, acc[1][0]); acc[1][1] = fmaf(a1, w.y, acc[1][1]);
      acc[1][2] = fmaf(a1, w.z, acc[1][2]); acc[1][3] = fmaf(a1, w.w, acc[1][3]);
    }
  }
  // fused alpha2: dot over 64 cols, reduce across the 16 ct lanes
  const float4 avs = *reinterpret_cast<const float4*>(&att_s[ct * 4]);
  const float4 avd = *reinterpret_cast<const float4*>(&att_d[ct * 4]);
  float ps[2], pd[2];
#pragma unroll
  for (int r = 0; r < 2; r++) {
    ps[r] = acc[r][0]*avs.x + acc[r][1]*avs.y + acc[r][2]*avs.z + acc[r][3]*avs.w;
    pd[r] = acc[r][0]*avd.x + acc[r][1]*avd.y + acc[r][2]*avd.z + acc[r][3]*avd.w;
#pragma unroll
    for (int o = 8; o > 0; o >>= 1) {
      ps[r] += __shfl_xor(ps[r], o, 64);
      pd[r] += __shfl_xor(pd[r], o, 64);
    }
  }
  if (((t & 63) & 15) == 0) {
#pragma unroll
    for (int r = 0; r < 2; r++) {
      const int row = row0 + rt * 2 + r;
      if (row < N) { as2[row] = ps[r]; ad2[row] = pd[r]; }
    }
  }
#pragma unroll
  for (int r = 0; r < 2; r++) {
    const int row = row0 + rt * 2 + r;
    if (row < N) {
      ushort4 ov;
      ov.x = f2bf(acc[r][0]); ov.y = f2bf(acc[r][1]);
      ov.z = f2bf(acc[r][2]); ov.w = f2bf(acc[r][3]);
      reinterpret_cast<ushort4*>(h2b + (size_t)row * 64)[ct] = ov;
    }
  }
}

// ---- gather2: bf16, half-wave per edge, 4-edge chunks per half ----
__global__ __launch_bounds__(256) void gather2w_kernel(
    const unsigned short* __restrict__ h2b, const float* __restrict__ w2,
    const float* __restrict__ wself2, const float* __restrict__ winv2,
    const float* __restrict__ b2, const int* __restrict__ row_start,
    const int* __restrict__ csr_src, float* __restrict__ h2, int N) {
  const int lane = threadIdx.x & 63;
  const int v = blockIdx.x * 4 + (threadIdx.x >> 6);
  if (v >= N) return;
  const int half = lane >> 5;   // 0/1: which edge of the pair
  const int cl = lane & 31;     // channels 2cl, 2cl+1
  const int rs = row_start[v], re = row_start[v + 1];
  float ax = 0.f, ay = 0.f;
  if (half == 0) {
    const unsigned int u = reinterpret_cast<const unsigned int*>(h2b + (size_t)v * 64)[cl];
    const float ws = wself2[v];
    ax = ws * bf2f(u & 0xffffu);
    ay = ws * bf2f(u >> 16);
  }
  if (rs < re) {
    const int rl = re - 1;
    int k = rs + half;
    int s0 = csr_src[min(k, rl)];
    int s1 = csr_src[min(k + 2, rl)];
    int s2 = csr_src[min(k + 4, rl)];
    int s3 = csr_src[min(k + 6, rl)];
    float t0 = w2[min(k, rl)];
    float t1 = w2[min(k + 2, rl)];
    float t2 = w2[min(k + 4, rl)];
    float t3 = w2[min(k + 6, rl)];
    float y0 = (k     < re) ? t0 : 0.f;
    float y1 = (k + 2 < re) ? t1 : 0.f;
    float y2 = (k + 4 < re) ? t2 : 0.f;
    float y3 = (k + 6 < re) ? t3 : 0.f;
    while (k < re) {
      const int kn = k + 8;
      const unsigned int f0 = reinterpret_cast<const unsigned int*>(h2b + (size_t)s0 * 64)[cl];
      const unsigned int f1 = reinterpret_cast<const unsigned int*>(h2b + (size_t)s1 * 64)[cl];
      const unsigned int f2 = reinterpret_cast<const unsigned int*>(h2b + (size_t)s2 * 64)[cl];
      const unsigned int f3 = reinterpret_cast<const unsigned int*>(h2b + (size_t)s3 * 64)[cl];
      const int kc0 = min(kn, rl), kc1 = min(kn + 2, rl), kc2 = min(kn + 4, rl), kc3 = min(kn + 6, rl);
      const int n0 = csr_src[kc0];
      const int n1 = csr_src[kc1];
      const int n2 = csr_src[kc2];
      const int n3 = csr_src[kc3];
      const float u0 = w2[kc0];
      const float u1 = w2[kc1];
      const float u2 = w2[kc2];
      const float u3 = w2[kc3];
      ax = fmaf(y0, bf2f(f0 & 0xffffu), ax); ay = fmaf(y0, bf2f(f0 >> 16), ay);
      ax = fmaf(y1, bf2f(f1 & 0xffffu), ax); ay = fmaf(y1, bf2f(f1 >> 16), ay);
      ax = fmaf(y2, bf2f(f2 & 0xffffu), ax); ay = fmaf(y2, bf2f(f2 >> 16), ay);
      ax = fmaf(y3, bf2f(f3 & 0xffffu), ax); ay = fmaf(y3, bf2f(f3 >> 16), ay);
      s0 = n0; s1 = n1; s2 = n2; s3 = n3;
      y0 = (kn     < re) ? u0 : 0.f;
      y1 = (kn + 2 < re) ? u1 : 0.f;
      y2 = (kn + 4 < re) ? u2 : 0.f;
      y3 = (kn + 6 < re) ? u3 : 0.f;
      k = kn;
    }
  }
  ax += __shfl_xor(ax, 32, 64);
  ay += __shfl_xor(ay, 32, 64);
  if (half == 0) {
    const float wi = winv2[v];
    float2 o;
    o.x = elu1(ax * wi + b2[2 * cl]);
    o.y = elu1(ay * wi + b2[2 * cl + 1]);
    reinterpret_cast<float2*>(h2 + (size_t)v * 64)[cl] = o;
  }
}

// ---------------- mean-pool over sorted batch ----------------
__global__ __launch_bounds__(256) void pool_kernel(
    const float* __restrict__ h2, const int* __restrict__ batch,
    float* __restrict__ pooled, float* __restrict__ cntf, int N) {
  const int lane = threadIdx.x & 63;
  const int gw = blockIdx.x * 4 + (threadIdx.x >> 6);
  const int s = gw * 64;
  if (s >= N) return;
  const int e = min(s + 64, N);
  int cur = batch[s];
  float racc = 0.f;
  int rc = 0;
  for (int v = s; v < e; v++) {
    const int g = batch[v];
    if (g != cur) {
      atomicAdd(&pooled[(size_t)cur * 64 + lane], racc);
      if (lane == 0) atomicAdd(&cntf[cur], (float)rc);
      racc = 0.f; rc = 0; cur = g;
    }
    racc += h2[(size_t)v * 64 + lane];
    rc++;
  }
  atomicAdd(&pooled[(size_t)cur * 64 + lane], racc);
  if (lane == 0) atomicAdd(&cntf[cur], (float)rc);
}

// ---------------- classifier ----------------
__global__ __launch_bounds__(64) void final_kernel(
    const float* __restrict__ pooled, const float* __restrict__ cntf,
    const float* __restrict__ Wc, const float* __restrict__ bc, float* __restrict__ out) {
  const int g = threadIdx.x;
  float acc = 0.f;
  for (int c = 0; c < 64; c++) acc = fmaf(pooled[(size_t)g * 64 + c], Wc[c], acc);
  const float cnt = fmaxf(cntf[g], 1.0f);
  out[g] = acc / cnt + bc[0];
}

extern "C" void kernel_launch(void* const* d_in, const int* in_sizes, int n_in,
                              void* d_out, int out_size, void* d_ws, size_t ws_size,
                              hipStream_t stream) {
  const float* x     = (const float*)d_in[0];
  const int*   ei    = (const int*)d_in[1];
  const int*   batch = (const int*)d_in[2];
  const float* W1    = (const float*)d_in[3];
  const float* atts1 = (const float*)d_in[4];
  const float* attd1 = (const float*)d_in[5];
  const float* b1    = (const float*)d_in[6];
  const float* W2    = (const float*)d_in[7];
  const float* atts2 = (const float*)d_in[8];
  const float* attd2 = (const float*)d_in[9];
  const float* b2    = (const float*)d_in[10];
  const float* Wc    = (const float*)d_in[11];
  const float* bc    = (const float*)d_in[12];
  float* out = (float*)d_out;

  const int N = in_sizes[0] / IN_F;   // 50000
  const int E = in_sizes[1] / 2;      // 800000
  const int* src = ei;
  const int* dst = ei + E;
  const int NB = (N + 255) / 256;     // scan blocks

  char* ws = (char*)d_ws;
  size_t off = 0;
  auto take = [&](size_t bytes) -> void* {
    void* p = ws + off;
    off = (off + bytes + 255) & ~(size_t)255;
    return p;
  };
  unsigned short* h1b   = (unsigned short*)take((size_t)N * 256 * 2);
  unsigned short* hmidb = (unsigned short*)take((size_t)N * 256 * 2);
  unsigned short* h2b   = (unsigned short*)take((size_t)N * 64 * 2);
  float* as1      = (float*)take((size_t)N * 4 * sizeof(float));
  float* ad1      = (float*)take((size_t)N * 4 * sizeof(float));
  float* as2      = (float*)take((size_t)N * sizeof(float));
  float* ad2      = (float*)take((size_t)N * sizeof(float));
  int*   cnt      = (int*)take((size_t)N * sizeof(int));
  int*   row_start= (int*)take((size_t)(N + 1) * sizeof(int));
  int*   cursor   = (int*)take((size_t)N * sizeof(int));
  int*   csr_src  = (int*)take((size_t)E * sizeof(int));
  int*   bsum     = (int*)take((size_t)NB * sizeof(int));
  int*   boff     = (int*)take((size_t)NB * sizeof(int));
  float* pooled   = (float*)take((size_t)GROUPS * 64 * sizeof(float));
  float* cntf     = (float*)take((size_t)GROUPS * sizeof(float));
  float* w1       = (float*)take((size_t)E * 4 * sizeof(float));
  float* wself1   = (float*)take((size_t)N * 4 * sizeof(float));
  float* winv1    = (float*)take((size_t)N * 4 * sizeof(float));
  float* h2       = (float*)take((size_t)N * 64 * sizeof(float));
  // conv2 edge buffers alias conv1's (dead after gather1w)
  float* w2     = w1;
  float* wself2 = wself1;
  float* winv2  = winv1;

  hipMemsetAsync(cnt, 0, (size_t)N * sizeof(int), stream);
  hipMemsetAsync(pooled, 0, (size_t)GROUPS * 64 * sizeof(float), stream);
  hipMemsetAsync(cntf, 0, (size_t)GROUPS * sizeof(float), stream);

  // conv1 linear + fused attention coefficients
  gemm1_kernel<<<(N + 63) / 64, 512, 0, stream>>>(x, W1, atts1, attd1, h1b, as1, ad1, N);

  // CSR by dst (multi-block scan)
  hist_kernel<<<(E + 255) / 256, 256, 0, stream>>>(dst, cnt, E);
  block_reduce_kernel<<<NB, 256, 0, stream>>>(cnt, bsum, N);
  bsum_scan_kernel<<<1, 256, 0, stream>>>(bsum, boff, NB);
  block_scan_kernel<<<NB, 256, 0, stream>>>(cnt, boff, row_start, cursor, N);
  scatter_kernel<<<(E + 255) / 256, 256, 0, stream>>>(src, dst, cursor, csr_src, E);

  // conv1: edge weights then pure gather
  edge_w1_kernel<<<(N + 7) / 8, 256, 0, stream>>>(as1, ad1, row_start, csr_src, w1, wself1, winv1, N);
  gather1w_kernel<<<(N + 3) / 4, 256, 0, stream>>>(h1b, w1, wself1, winv1, b1, row_start, csr_src, hmidb, N);

  // conv2
  gemm2_kernel<<<(N + 31) / 32, 256, 0, stream>>>(hmidb, W2, atts2, attd2, h2b, as2, ad2, N);
  edge_w2_kernel<<<(N + 7) / 8, 256, 0, stream>>>(as2, ad2, row_start, csr_src, w2, wself2, winv2, N);
  gather2w_kernel<<<(N + 3) / 4, 256, 0, stream>>>(h2b, w2, wself2, winv2, b2, row_start, csr_src, h2, N);

  // pooling + classifier
  pool_kernel<<<((N + 63) / 64 + 3) / 4, 256, 0, stream>>>(h2, batch, pooled, cntf, N);
  final_kernel<<<1, 64, 0, stream>>>(pooled, cntf, Wc, bc, out);

  (void)n_in; (void)out_size; (void)ws_size;
}